// Round 1
// baseline (1114.216 us; speedup 1.0000x reference)
//
#include <hip/hip_runtime.h>

#define T_SEQ 1024
#define C_DIM 1024
#define H_DIM 4096
#define M_ROWS 16384   // P*B*T = 2*8*1024

typedef _Float16 f16x8 __attribute__((ext_vector_type(8)));
typedef _Float16 f16x4 __attribute__((ext_vector_type(4)));
typedef float    f32x4 __attribute__((ext_vector_type(4)));

#define AS1 __attribute__((address_space(1)))
#define AS3 __attribute__((address_space(3)))

__device__ __forceinline__ void gload_lds16(const void* g, void* l) {
  __builtin_amdgcn_global_load_lds((const AS1 void*)g, (AS3 void*)l, 16, 0, 0);
}

__device__ __forceinline__ float sigmoidf_(float x) {
  return 1.0f / (1.0f + __expf(-x));
}

// ---------------- weight f32 -> f16 ----------------
__global__ __launch_bounds__(256) void cvt_kernel(const float* __restrict__ in,
                                                  _Float16* __restrict__ out, int n4) {
  int i = blockIdx.x * 256 + threadIdx.x;
  if (i >= n4) return;
  f32x4 v = reinterpret_cast<const f32x4*>(in)[i];
  f16x4 o;
  o[0] = (_Float16)v[0]; o[1] = (_Float16)v[1];
  o[2] = (_Float16)v[2]; o[3] = (_Float16)v[3];
  reinterpret_cast<f16x4*>(out)[i] = o;
}

// ---------------- layernorm: f32 in -> f16 out (one wave per row) ----------------
__global__ __launch_bounds__(256) void ln_kernel(const float* __restrict__ x,
    const float* __restrict__ g, const float* __restrict__ b,
    _Float16* __restrict__ h) {
  const int row  = blockIdx.x * 4 + (threadIdx.x >> 6);
  const int lane = threadIdx.x & 63;
  const f32x4* xr = reinterpret_cast<const f32x4*>(x + (size_t)row * C_DIM);
  f32x4 v[4];
  float s = 0.f, sq = 0.f;
#pragma unroll
  for (int i = 0; i < 4; ++i) {
    v[i] = xr[i * 64 + lane];
#pragma unroll
    for (int j = 0; j < 4; ++j) { s += v[i][j]; sq += v[i][j] * v[i][j]; }
  }
#pragma unroll
  for (int off = 32; off > 0; off >>= 1) {
    s  += __shfl_xor(s, off, 64);
    sq += __shfl_xor(sq, off, 64);
  }
  const float mu   = s * (1.0f / C_DIM);
  const float var  = sq * (1.0f / C_DIM) - mu * mu;
  const float rstd = rsqrtf(var + 1e-5f);
  const f32x4* g4 = reinterpret_cast<const f32x4*>(g);
  const f32x4* b4 = reinterpret_cast<const f32x4*>(b);
  f16x4* h4 = reinterpret_cast<f16x4*>(h + (size_t)row * C_DIM);
#pragma unroll
  for (int i = 0; i < 4; ++i) {
    f32x4 gg = g4[i * 64 + lane];
    f32x4 bb = b4[i * 64 + lane];
    f16x4 o;
#pragma unroll
    for (int j = 0; j < 4; ++j)
      o[j] = (_Float16)((v[i][j] - mu) * rstd * gg[j] + bb[j]);
    h4[i * 64 + lane] = o;
  }
}

// ---------------- time-shift mix, 3 outputs ----------------
__global__ __launch_bounds__(256) void mix3_kernel(const _Float16* __restrict__ h,
    const float* __restrict__ mk, const float* __restrict__ mv, const float* __restrict__ mr,
    _Float16* __restrict__ xk, _Float16* __restrict__ xv, _Float16* __restrict__ xr) {
  const int i  = blockIdx.x * 256 + threadIdx.x;   // [0, M_ROWS*128)
  const int m  = i >> 7;
  const int c0 = (i & 127) << 3;
  const int p  = m >> 13;
  const int t  = m & (T_SEQ - 1);
  const f16x8* h8 = reinterpret_cast<const f16x8*>(h);
  f16x8 hc = h8[i];
  f16x8 hp;
#pragma unroll
  for (int j = 0; j < 8; ++j) hp[j] = (_Float16)0.f;
  if (t) hp = h8[i - 128];
  f16x8 ok, ov, orr;
#pragma unroll
  for (int j = 0; j < 8; ++j) {
    const float hcf = (float)hc[j], hpf = (float)hp[j];
    const float a = mk[p * C_DIM + c0 + j];
    const float c = mv[p * C_DIM + c0 + j];
    const float d = mr[p * C_DIM + c0 + j];
    ok[j]  = (_Float16)(hcf * a + hpf * (1.f - a));
    ov[j]  = (_Float16)(hcf * c + hpf * (1.f - c));
    orr[j] = (_Float16)(hcf * d + hpf * (1.f - d));
  }
  reinterpret_cast<f16x8*>(xk)[i] = ok;
  reinterpret_cast<f16x8*>(xv)[i] = ov;
  reinterpret_cast<f16x8*>(xr)[i] = orr;
}

// ---------------- time-shift mix, 2 outputs ----------------
__global__ __launch_bounds__(256) void mix2_kernel(const _Float16* __restrict__ h,
    const float* __restrict__ mk, const float* __restrict__ mr,
    _Float16* __restrict__ xk, _Float16* __restrict__ xr) {
  const int i  = blockIdx.x * 256 + threadIdx.x;
  const int m  = i >> 7;
  const int c0 = (i & 127) << 3;
  const int p  = m >> 13;
  const int t  = m & (T_SEQ - 1);
  const f16x8* h8 = reinterpret_cast<const f16x8*>(h);
  f16x8 hc = h8[i];
  f16x8 hp;
#pragma unroll
  for (int j = 0; j < 8; ++j) hp[j] = (_Float16)0.f;
  if (t) hp = h8[i - 128];
  f16x8 ok, orr;
#pragma unroll
  for (int j = 0; j < 8; ++j) {
    const float hcf = (float)hc[j], hpf = (float)hp[j];
    const float a = mk[p * C_DIM + c0 + j];
    const float d = mr[p * C_DIM + c0 + j];
    ok[j]  = (_Float16)(hcf * a + hpf * (1.f - a));
    orr[j] = (_Float16)(hcf * d + hpf * (1.f - d));
  }
  reinterpret_cast<f16x8*>(xk)[i] = ok;
  reinterpret_cast<f16x8*>(xr)[i] = orr;
}

// ---------------- WKV serial scan (one thread per (seq, channel)) ----------------
__global__ __launch_bounds__(64) void wkv_kernel(const _Float16* __restrict__ k,
    const _Float16* __restrict__ v, const float* __restrict__ td,
    const float* __restrict__ tf, _Float16* __restrict__ y) {
  const int gid = blockIdx.x * 64 + threadIdx.x;   // [0, 16384)
  const int c   = gid & (C_DIM - 1);
  const size_t base = (size_t)(gid >> 10) * T_SEQ * C_DIM + c;
  const float w = -__expf(td[c]);
  const float u = tf[c];
  float aa = 0.f, bb = 0.f, pp = -1e38f;
  float kk = (float)k[base], vv = (float)v[base];
  for (int t = 0; t < T_SEQ; ++t) {
    float kn = 0.f, vn = 0.f;
    if (t + 1 < T_SEQ) {
      const size_t nidx = base + (size_t)(t + 1) * C_DIM;
      kn = (float)k[nidx];
      vn = (float)v[nidx];
    }
    const float ww = u + kk;
    const float p  = fmaxf(pp, ww);
    const float e1 = __expf(pp - p);
    const float e2 = __expf(ww - p);
    const float yv = __fdividef(e1 * aa + e2 * vv, e1 * bb + e2);
    y[base + (size_t)t * C_DIM] = (_Float16)yv;
    const float ww2 = w + pp;
    const float p2  = fmaxf(ww2, kk);
    const float e1b = __expf(ww2 - p2);
    const float e2b = __expf(kk - p2);
    aa = e1b * aa + e2b * vv;
    bb = e1b * bb + e2b;
    pp = p2;
    kk = kn; vv = vn;
  }
}

// ---------------- a = f16(sigmoid(r) * y) ----------------
__global__ __launch_bounds__(256) void srmul_kernel(const _Float16* __restrict__ r,
    const _Float16* __restrict__ y, _Float16* __restrict__ a) {
  const int i = blockIdx.x * 256 + threadIdx.x;   // over M_ROWS*128
  f16x8 rv = reinterpret_cast<const f16x8*>(r)[i];
  f16x8 yv = reinterpret_cast<const f16x8*>(y)[i];
  f16x8 o;
#pragma unroll
  for (int j = 0; j < 8; ++j)
    o[j] = (_Float16)(sigmoidf_((float)rv[j]) * (float)yv[j]);
  reinterpret_cast<f16x8*>(a)[i] = o;
}

// ---------------- out += sigmoid(rr) * kv ----------------
__global__ __launch_bounds__(256) void final_kernel(float* __restrict__ out,
    const _Float16* __restrict__ rr, const _Float16* __restrict__ kv) {
  const int i = blockIdx.x * 256 + threadIdx.x;   // over M_ROWS*256 (4 elems each)
  f32x4 o = reinterpret_cast<f32x4*>(out)[i];
  f16x4 rv = reinterpret_cast<const f16x4*>(rr)[i];
  f16x4 kvv = reinterpret_cast<const f16x4*>(kv)[i];
#pragma unroll
  for (int j = 0; j < 4; ++j)
    o[j] += sigmoidf_((float)rv[j]) * (float)kvv[j];
  reinterpret_cast<f32x4*>(out)[i] = o;
}

// ---------------- GEMM: C[M,N] = A[M,K] * B[N,K]^T  (f16 in, f32 acc) ----------------
// EPI 0: store f16; EPI 1: store f16(relu(acc)^2); EPI 2: store f32 acc + X
template<int EPI>
__global__ __launch_bounds__(256) void gemm_nt_kernel(
    const _Float16* __restrict__ A, const _Float16* __restrict__ B,
    void* __restrict__ Cv, const float* __restrict__ X,
    int M, int N, int K) {
  __shared__ _Float16 lA[128 * 64];
  __shared__ _Float16 lB[128 * 64];
  const int tid  = threadIdx.x;
  const int wave = tid >> 6;
  const int lane = tid & 63;
  const int wr   = wave >> 1;
  const int wc   = wave & 1;
  const size_t m0 = (size_t)blockIdx.y * 128;
  const size_t n0 = (size_t)blockIdx.x * 128;

  // staging: 16 chunks of 1KB; wave w stages chunks w*4..w*4+3 for A and B
  const int srow = lane >> 3;          // 0..7
  const int scol = (lane & 7) * 8;     // 0..56 (halfs)
  const _Float16* pA[4];
  const _Float16* pB[4];
#pragma unroll
  for (int i = 0; i < 4; ++i) {
    const int chunk = wave * 4 + i;
    pA[i] = A + (m0 + (size_t)(chunk * 8 + srow)) * K + scol;
    pB[i] = B + (n0 + (size_t)(chunk * 8 + srow)) * K + scol;
  }
  const int frow = lane & 15;
  const int fk   = (lane >> 4) * 8;

  const f32x4 zf = {0.f, 0.f, 0.f, 0.f};
  f32x4 acc[4][4];
#pragma unroll
  for (int i = 0; i < 4; ++i)
#pragma unroll
    for (int j = 0; j < 4; ++j) acc[i][j] = zf;

  for (int k0 = 0; k0 < K; k0 += 64) {
#pragma unroll
    for (int i = 0; i < 4; ++i)
      gload_lds16(pA[i] + k0, &lA[(wave * 4 + i) * 512]);
#pragma unroll
    for (int i = 0; i < 4; ++i)
      gload_lds16(pB[i] + k0, &lB[(wave * 4 + i) * 512]);
    __syncthreads();
#pragma unroll
    for (int kk = 0; kk < 64; kk += 32) {
      f16x8 af[4], bf[4];
#pragma unroll
      for (int i = 0; i < 4; ++i)
        af[i] = *reinterpret_cast<const f16x8*>(&lA[(wr * 64 + i * 16 + frow) * 64 + kk + fk]);
#pragma unroll
      for (int j = 0; j < 4; ++j)
        bf[j] = *reinterpret_cast<const f16x8*>(&lB[(wc * 64 + j * 16 + frow) * 64 + kk + fk]);
#pragma unroll
      for (int i = 0; i < 4; ++i)
#pragma unroll
        for (int j = 0; j < 4; ++j)
          acc[i][j] = __builtin_amdgcn_mfma_f32_16x16x32_f16(af[i], bf[j], acc[i][j], 0, 0, 0);
    }
    __syncthreads();
  }

  // epilogue: C/D layout (16x16): col = lane&15, row = (lane>>4)*4 + reg
  const int ecol = lane & 15;
  const int erow = (lane >> 4) * 4;
#pragma unroll
  for (int i = 0; i < 4; ++i)
#pragma unroll
    for (int j = 0; j < 4; ++j) {
      const size_t rbase = m0 + (size_t)(wr * 64 + i * 16 + erow);
      const size_t cc    = n0 + (size_t)(wc * 64 + j * 16 + ecol);
#pragma unroll
      for (int r = 0; r < 4; ++r) {
        const float val = acc[i][j][r];
        const size_t off = (rbase + r) * (size_t)N + cc;
        if constexpr (EPI == 0) {
          ((_Float16*)Cv)[off] = (_Float16)val;
        } else if constexpr (EPI == 1) {
          const float t = fmaxf(val, 0.f);
          ((_Float16*)Cv)[off] = (_Float16)(t * t);
        } else {
          ((float*)Cv)[off] = val + X[off];
        }
      }
    }
}

extern "C" void kernel_launch(void* const* d_in, const int* in_sizes, int n_in,
                              void* d_out, int out_size, void* d_ws, size_t ws_size,
                              hipStream_t stream) {
  const float* x      = (const float*)d_in[0];
  const float* ln1_g  = (const float*)d_in[1];
  const float* ln1_b  = (const float*)d_in[2];
  const float* ln2_g  = (const float*)d_in[3];
  const float* ln2_b  = (const float*)d_in[4];
  const float* tdec   = (const float*)d_in[5];
  const float* tfirst = (const float*)d_in[6];
  const float* amk    = (const float*)d_in[7];
  const float* amv    = (const float*)d_in[8];
  const float* amr    = (const float*)d_in[9];
  const float* Wk     = (const float*)d_in[10];
  const float* Wv     = (const float*)d_in[11];
  const float* Wr     = (const float*)d_in[12];
  const float* Wo     = (const float*)d_in[13];
  const float* cmk    = (const float*)d_in[14];
  const float* cmr    = (const float*)d_in[15];
  const float* Wck    = (const float*)d_in[16];
  const float* Wcr    = (const float*)d_in[17];
  const float* Wcv    = (const float*)d_in[18];

  char* ws = (char*)d_ws;
  const size_t SZ = (size_t)M_ROWS * C_DIM * sizeof(_Float16);  // 32 MiB
  _Float16* B0 = (_Float16*)(ws + 0 * SZ);
  _Float16* B1 = (_Float16*)(ws + 1 * SZ);
  _Float16* B2 = (_Float16*)(ws + 2 * SZ);
  _Float16* B3 = (_Float16*)(ws + 3 * SZ);   // kk spans B3..B6 (128 MiB)
  _Float16* B4 = (_Float16*)(ws + 4 * SZ);
  _Float16* B5 = (_Float16*)(ws + 5 * SZ);
  _Float16* B6 = (_Float16*)(ws + 6 * SZ);
  _Float16* wWk  = (_Float16*)(ws + 7 * SZ);
  _Float16* wWv  = wWk  + (size_t)C_DIM * C_DIM;
  _Float16* wWr  = wWv  + (size_t)C_DIM * C_DIM;
  _Float16* wWo  = wWr  + (size_t)C_DIM * C_DIM;
  _Float16* wWcr = wWo  + (size_t)C_DIM * C_DIM;
  _Float16* wWck = wWcr + (size_t)C_DIM * C_DIM;
  _Float16* wWcv = wWck + (size_t)H_DIM * C_DIM;

  auto cvt = [&](const float* src, _Float16* dst, size_t n) {
    const int n4 = (int)(n / 4);
    cvt_kernel<<<dim3((n4 + 255) / 256), dim3(256), 0, stream>>>(src, dst, n4);
  };
  cvt(Wk,  wWk,  (size_t)C_DIM * C_DIM);
  cvt(Wv,  wWv,  (size_t)C_DIM * C_DIM);
  cvt(Wr,  wWr,  (size_t)C_DIM * C_DIM);
  cvt(Wo,  wWo,  (size_t)C_DIM * C_DIM);
  cvt(Wcr, wWcr, (size_t)C_DIM * C_DIM);
  cvt(Wck, wWck, (size_t)H_DIM * C_DIM);
  cvt(Wcv, wWcv, (size_t)C_DIM * H_DIM);

  const dim3 blk(256);
  const dim3 gN1(C_DIM / 128, M_ROWS / 128);   // (8, 128)
  const dim3 gN4(H_DIM / 128, M_ROWS / 128);   // (32, 128)

  // --- TimeMix ---
  ln_kernel<<<dim3(M_ROWS / 4), blk, 0, stream>>>(x, ln1_g, ln1_b, B0);
  mix3_kernel<<<dim3(M_ROWS * 128 / 256), blk, 0, stream>>>(B0, amk, amv, amr, B1, B2, B3);
  gemm_nt_kernel<0><<<gN1, blk, 0, stream>>>(B1, wWk, B4, nullptr, M_ROWS, C_DIM, C_DIM);
  gemm_nt_kernel<0><<<gN1, blk, 0, stream>>>(B2, wWv, B5, nullptr, M_ROWS, C_DIM, C_DIM);
  gemm_nt_kernel<0><<<gN1, blk, 0, stream>>>(B3, wWr, B6, nullptr, M_ROWS, C_DIM, C_DIM);
  wkv_kernel<<<dim3(16384 / 64), dim3(64), 0, stream>>>(B4, B5, tdec, tfirst, B0);
  srmul_kernel<<<dim3(M_ROWS * 128 / 256), blk, 0, stream>>>(B6, B0, B1);
  gemm_nt_kernel<2><<<gN1, blk, 0, stream>>>(B1, wWo, d_out, x, M_ROWS, C_DIM, C_DIM);

  // --- ChannelMix ---
  ln_kernel<<<dim3(M_ROWS / 4), blk, 0, stream>>>((const float*)d_out, ln2_g, ln2_b, B0);
  mix2_kernel<<<dim3(M_ROWS * 128 / 256), blk, 0, stream>>>(B0, cmk, cmr, B1, B2);
  gemm_nt_kernel<1><<<gN4, blk, 0, stream>>>(B1, wWck, B3, nullptr, M_ROWS, H_DIM, C_DIM);
  gemm_nt_kernel<0><<<gN1, blk, 0, stream>>>(B3, wWcv, B1, nullptr, M_ROWS, C_DIM, H_DIM);
  gemm_nt_kernel<0><<<gN1, blk, 0, stream>>>(B2, wWcr, B0, nullptr, M_ROWS, C_DIM, C_DIM);
  final_kernel<<<dim3(M_ROWS * 256 / 256), blk, 0, stream>>>((float*)d_out, B0, B1);
}

// Round 2
// 1055.342 us; speedup vs baseline: 1.0558x; 1.0558x over previous
//
#include <hip/hip_runtime.h>

#define T_SEQ 1024
#define C_DIM 1024
#define H_DIM 4096
#define M_ROWS 16384   // P*B*T = 2*8*1024

typedef _Float16 f16x8 __attribute__((ext_vector_type(8)));
typedef _Float16 f16x4 __attribute__((ext_vector_type(4)));
typedef float    f32x4 __attribute__((ext_vector_type(4)));

#define AS1 __attribute__((address_space(1)))
#define AS3 __attribute__((address_space(3)))

__device__ __forceinline__ void gload_lds16(const void* g, void* l) {
  __builtin_amdgcn_global_load_lds((const AS1 void*)g, (AS3 void*)l, 16, 0, 0);
}

__device__ __forceinline__ float sigmoidf_(float x) {
  return 1.0f / (1.0f + __expf(-x));
}

// ---------------- weight f32 -> f16 ----------------
__global__ __launch_bounds__(256) void cvt_kernel(const float* __restrict__ in,
                                                  _Float16* __restrict__ out, int n4) {
  int i = blockIdx.x * 256 + threadIdx.x;
  if (i >= n4) return;
  f32x4 v = reinterpret_cast<const f32x4*>(in)[i];
  f16x4 o;
  o[0] = (_Float16)v[0]; o[1] = (_Float16)v[1];
  o[2] = (_Float16)v[2]; o[3] = (_Float16)v[3];
  reinterpret_cast<f16x4*>(out)[i] = o;
}

// ---------------- layernorm: f32 in -> f16 out (one wave per row) ----------------
__global__ __launch_bounds__(256) void ln_kernel(const float* __restrict__ x,
    const float* __restrict__ g, const float* __restrict__ b,
    _Float16* __restrict__ h) {
  const int row  = blockIdx.x * 4 + (threadIdx.x >> 6);
  const int lane = threadIdx.x & 63;
  const f32x4* xr = reinterpret_cast<const f32x4*>(x + (size_t)row * C_DIM);
  f32x4 v[4];
  float s = 0.f, sq = 0.f;
#pragma unroll
  for (int i = 0; i < 4; ++i) {
    v[i] = xr[i * 64 + lane];
#pragma unroll
    for (int j = 0; j < 4; ++j) { s += v[i][j]; sq += v[i][j] * v[i][j]; }
  }
#pragma unroll
  for (int off = 32; off > 0; off >>= 1) {
    s  += __shfl_xor(s, off, 64);
    sq += __shfl_xor(sq, off, 64);
  }
  const float mu   = s * (1.0f / C_DIM);
  const float var  = sq * (1.0f / C_DIM) - mu * mu;
  const float rstd = rsqrtf(var + 1e-5f);
  const f32x4* g4 = reinterpret_cast<const f32x4*>(g);
  const f32x4* b4 = reinterpret_cast<const f32x4*>(b);
  f16x4* h4 = reinterpret_cast<f16x4*>(h + (size_t)row * C_DIM);
#pragma unroll
  for (int i = 0; i < 4; ++i) {
    f32x4 gg = g4[i * 64 + lane];
    f32x4 bb = b4[i * 64 + lane];
    f16x4 o;
#pragma unroll
    for (int j = 0; j < 4; ++j)
      o[j] = (_Float16)((v[i][j] - mu) * rstd * gg[j] + bb[j]);
    h4[i * 64 + lane] = o;
  }
}

// ---------------- time-shift mix, 3 outputs ----------------
__global__ __launch_bounds__(256) void mix3_kernel(const _Float16* __restrict__ h,
    const float* __restrict__ mk, const float* __restrict__ mv, const float* __restrict__ mr,
    _Float16* __restrict__ xk, _Float16* __restrict__ xv, _Float16* __restrict__ xr) {
  const int i  = blockIdx.x * 256 + threadIdx.x;   // [0, M_ROWS*128)
  const int m  = i >> 7;
  const int c0 = (i & 127) << 3;
  const int p  = m >> 13;
  const int t  = m & (T_SEQ - 1);
  const f16x8* h8 = reinterpret_cast<const f16x8*>(h);
  f16x8 hc = h8[i];
  f16x8 hp;
#pragma unroll
  for (int j = 0; j < 8; ++j) hp[j] = (_Float16)0.f;
  if (t) hp = h8[i - 128];
  f16x8 ok, ov, orr;
#pragma unroll
  for (int j = 0; j < 8; ++j) {
    const float hcf = (float)hc[j], hpf = (float)hp[j];
    const float a = mk[p * C_DIM + c0 + j];
    const float c = mv[p * C_DIM + c0 + j];
    const float d = mr[p * C_DIM + c0 + j];
    ok[j]  = (_Float16)(hcf * a + hpf * (1.f - a));
    ov[j]  = (_Float16)(hcf * c + hpf * (1.f - c));
    orr[j] = (_Float16)(hcf * d + hpf * (1.f - d));
  }
  reinterpret_cast<f16x8*>(xk)[i] = ok;
  reinterpret_cast<f16x8*>(xv)[i] = ov;
  reinterpret_cast<f16x8*>(xr)[i] = orr;
}

// ---------------- time-shift mix, 2 outputs ----------------
__global__ __launch_bounds__(256) void mix2_kernel(const _Float16* __restrict__ h,
    const float* __restrict__ mk, const float* __restrict__ mr,
    _Float16* __restrict__ xk, _Float16* __restrict__ xr) {
  const int i  = blockIdx.x * 256 + threadIdx.x;
  const int m  = i >> 7;
  const int c0 = (i & 127) << 3;
  const int p  = m >> 13;
  const int t  = m & (T_SEQ - 1);
  const f16x8* h8 = reinterpret_cast<const f16x8*>(h);
  f16x8 hc = h8[i];
  f16x8 hp;
#pragma unroll
  for (int j = 0; j < 8; ++j) hp[j] = (_Float16)0.f;
  if (t) hp = h8[i - 128];
  f16x8 ok, orr;
#pragma unroll
  for (int j = 0; j < 8; ++j) {
    const float hcf = (float)hc[j], hpf = (float)hp[j];
    const float a = mk[p * C_DIM + c0 + j];
    const float d = mr[p * C_DIM + c0 + j];
    ok[j]  = (_Float16)(hcf * a + hpf * (1.f - a));
    orr[j] = (_Float16)(hcf * d + hpf * (1.f - d));
  }
  reinterpret_cast<f16x8*>(xk)[i] = ok;
  reinterpret_cast<f16x8*>(xr)[i] = orr;
}

// ---------------- WKV serial scan fused with a = sigmoid(r)*y ----------------
__global__ __launch_bounds__(64) void wkv_kernel(const _Float16* __restrict__ k,
    const _Float16* __restrict__ v, const _Float16* __restrict__ r,
    const float* __restrict__ td, const float* __restrict__ tf,
    _Float16* __restrict__ a_out) {
  const int gid = blockIdx.x * 64 + threadIdx.x;   // [0, 16384)
  const int c   = gid & (C_DIM - 1);
  const size_t base = (size_t)(gid >> 10) * T_SEQ * C_DIM + c;
  const float w = -__expf(td[c]);
  const float u = tf[c];
  float aa = 0.f, bb = 0.f, pp = -1e38f;
  float kk = (float)k[base], vv = (float)v[base];
  for (int t = 0; t < T_SEQ; ++t) {
    const size_t idx = base + (size_t)t * C_DIM;
    float kn = 0.f, vn = 0.f;
    if (t + 1 < T_SEQ) {
      kn = (float)k[idx + C_DIM];
      vn = (float)v[idx + C_DIM];
    }
    const float ww = u + kk;
    const float p  = fmaxf(pp, ww);
    const float e1 = __expf(pp - p);
    const float e2 = __expf(ww - p);
    const float yv = __fdividef(e1 * aa + e2 * vv, e1 * bb + e2);
    const float sr = sigmoidf_((float)r[idx]);
    a_out[idx] = (_Float16)(sr * yv);
    const float ww2 = w + pp;
    const float p2  = fmaxf(ww2, kk);
    const float e1b = __expf(ww2 - p2);
    const float e2b = __expf(kk - p2);
    aa = e1b * aa + e2b * vv;
    bb = e1b * bb + e2b;
    pp = p2;
    kk = kn; vv = vn;
  }
}

// ---------------- GEMM: C[M,N] = A[M,K] * B[N,K]^T  (f16 in, f32 acc) ----------------
// EPI 0: store f16
// EPI 1: store f16(relu(acc)^2)
// EPI 2: store f32 (acc + X)
// EPI 3: store f32 (X + sigmoid(acc) * KV)
template<int EPI>
__global__ __launch_bounds__(256) void gemm_nt_kernel(
    const _Float16* __restrict__ A, const _Float16* __restrict__ B,
    void* __restrict__ Cv, const float* __restrict__ X,
    const _Float16* __restrict__ KV, int M, int N, int K) {
  __shared__ _Float16 lA[128 * 64];
  __shared__ _Float16 lB[128 * 64];
  const int tid  = threadIdx.x;
  const int wave = tid >> 6;
  const int lane = tid & 63;
  const int wr   = wave >> 1;
  const int wc   = wave & 1;

  // XCD-bijective swizzle: XCD (= linear_id % 8) owns a contiguous M chunk,
  // n-fastest within (A panel reuse in L2; B panel streams L2/L3-resident).
  const unsigned nwx = gridDim.x;                 // N/128
  const unsigned per = gridDim.y >> 3;            // m-tiles per XCD (gridDim.y % 8 == 0)
  const unsigned id  = blockIdx.y * nwx + blockIdx.x;
  const unsigned xcd = id & 7;
  const unsigned loc = id >> 3;
  const size_t m0 = (size_t)(xcd * per + loc / nwx) * 128;
  const size_t n0 = (size_t)(loc % nwx) * 128;

  // staging: 16 chunks of 1KB; wave w stages chunks w*4..w*4+3 for A and B.
  // LDS dest is LINEAR (global_load_lds requirement); the T2 st-swizzle is
  // applied by XOR-permuting the SOURCE 16B-slot within each 128B row
  // (involution), and the same XOR on the ds_read side.
  const int srow = lane >> 3;                          // 0..7 (row within chunk)
  const int scol = ((lane & 7) ^ srow) * 8;            // swizzled col (halfs)
  const _Float16* pA[4];
  const _Float16* pB[4];
#pragma unroll
  for (int i = 0; i < 4; ++i) {
    const int chunk = wave * 4 + i;
    pA[i] = A + (m0 + (size_t)(chunk * 8 + srow)) * K + scol;
    pB[i] = B + (n0 + (size_t)(chunk * 8 + srow)) * K + scol;
  }
  const int frow = lane & 15;
  const int fk   = (lane >> 4) * 8;
  const int fxor = (frow & 7) << 3;                    // read-side XOR (halfs)

  const f32x4 zf = {0.f, 0.f, 0.f, 0.f};
  f32x4 acc[4][4];
#pragma unroll
  for (int i = 0; i < 4; ++i)
#pragma unroll
    for (int j = 0; j < 4; ++j) acc[i][j] = zf;

  for (int k0 = 0; k0 < K; k0 += 64) {
#pragma unroll
    for (int i = 0; i < 4; ++i)
      gload_lds16(pA[i] + k0, &lA[(wave * 4 + i) * 512]);
#pragma unroll
    for (int i = 0; i < 4; ++i)
      gload_lds16(pB[i] + k0, &lB[(wave * 4 + i) * 512]);
    __syncthreads();
#pragma unroll
    for (int kk = 0; kk < 64; kk += 32) {
      f16x8 af[4], bf[4];
#pragma unroll
      for (int i = 0; i < 4; ++i)
        af[i] = *reinterpret_cast<const f16x8*>(
            &lA[(wr * 64 + i * 16 + frow) * 64 + ((kk + fk) ^ fxor)]);
#pragma unroll
      for (int j = 0; j < 4; ++j)
        bf[j] = *reinterpret_cast<const f16x8*>(
            &lB[(wc * 64 + j * 16 + frow) * 64 + ((kk + fk) ^ fxor)]);
#pragma unroll
      for (int i = 0; i < 4; ++i)
#pragma unroll
        for (int j = 0; j < 4; ++j)
          acc[i][j] = __builtin_amdgcn_mfma_f32_16x16x32_f16(af[i], bf[j], acc[i][j], 0, 0, 0);
    }
    __syncthreads();
  }

  // epilogue: C/D layout (16x16): col = lane&15, row = (lane>>4)*4 + reg
  const int ecol = lane & 15;
  const int erow = (lane >> 4) * 4;
#pragma unroll
  for (int i = 0; i < 4; ++i)
#pragma unroll
    for (int j = 0; j < 4; ++j) {
      const size_t rbase = m0 + (size_t)(wr * 64 + i * 16 + erow);
      const size_t cc    = n0 + (size_t)(wc * 64 + j * 16 + ecol);
#pragma unroll
      for (int r = 0; r < 4; ++r) {
        const float val = acc[i][j][r];
        const size_t off = (rbase + r) * (size_t)N + cc;
        if constexpr (EPI == 0) {
          ((_Float16*)Cv)[off] = (_Float16)val;
        } else if constexpr (EPI == 1) {
          const float t = fmaxf(val, 0.f);
          ((_Float16*)Cv)[off] = (_Float16)(t * t);
        } else if constexpr (EPI == 2) {
          ((float*)Cv)[off] = val + X[off];
        } else {
          ((float*)Cv)[off] = X[off] + sigmoidf_(val) * (float)KV[off];
        }
      }
    }
}

extern "C" void kernel_launch(void* const* d_in, const int* in_sizes, int n_in,
                              void* d_out, int out_size, void* d_ws, size_t ws_size,
                              hipStream_t stream) {
  const float* x      = (const float*)d_in[0];
  const float* ln1_g  = (const float*)d_in[1];
  const float* ln1_b  = (const float*)d_in[2];
  const float* ln2_g  = (const float*)d_in[3];
  const float* ln2_b  = (const float*)d_in[4];
  const float* tdec   = (const float*)d_in[5];
  const float* tfirst = (const float*)d_in[6];
  const float* amk    = (const float*)d_in[7];
  const float* amv    = (const float*)d_in[8];
  const float* amr    = (const float*)d_in[9];
  const float* Wk     = (const float*)d_in[10];
  const float* Wv     = (const float*)d_in[11];
  const float* Wr     = (const float*)d_in[12];
  const float* Wo     = (const float*)d_in[13];
  const float* cmk    = (const float*)d_in[14];
  const float* cmr    = (const float*)d_in[15];
  const float* Wck    = (const float*)d_in[16];
  const float* Wcr    = (const float*)d_in[17];
  const float* Wcv    = (const float*)d_in[18];

  char* ws = (char*)d_ws;
  const size_t SZ = (size_t)M_ROWS * C_DIM * sizeof(_Float16);  // 32 MiB
  _Float16* B0 = (_Float16*)(ws + 0 * SZ);
  _Float16* B1 = (_Float16*)(ws + 1 * SZ);
  _Float16* B2 = (_Float16*)(ws + 2 * SZ);
  _Float16* B3 = (_Float16*)(ws + 3 * SZ);   // kk spans B3..B6 (128 MiB)
  _Float16* B4 = (_Float16*)(ws + 4 * SZ);
  _Float16* B5 = (_Float16*)(ws + 5 * SZ);
  _Float16* B6 = (_Float16*)(ws + 6 * SZ);
  _Float16* wWk  = (_Float16*)(ws + 7 * SZ);
  _Float16* wWv  = wWk  + (size_t)C_DIM * C_DIM;
  _Float16* wWr  = wWv  + (size_t)C_DIM * C_DIM;
  _Float16* wWo  = wWr  + (size_t)C_DIM * C_DIM;
  _Float16* wWcr = wWo  + (size_t)C_DIM * C_DIM;
  _Float16* wWck = wWcr + (size_t)C_DIM * C_DIM;
  _Float16* wWcv = wWck + (size_t)H_DIM * C_DIM;

  auto cvt = [&](const float* src, _Float16* dst, size_t n) {
    const int n4 = (int)(n / 4);
    cvt_kernel<<<dim3((n4 + 255) / 256), dim3(256), 0, stream>>>(src, dst, n4);
  };
  cvt(Wk,  wWk,  (size_t)C_DIM * C_DIM);
  cvt(Wv,  wWv,  (size_t)C_DIM * C_DIM);
  cvt(Wr,  wWr,  (size_t)C_DIM * C_DIM);
  cvt(Wo,  wWo,  (size_t)C_DIM * C_DIM);
  cvt(Wcr, wWcr, (size_t)C_DIM * C_DIM);
  cvt(Wck, wWck, (size_t)H_DIM * C_DIM);
  cvt(Wcv, wWcv, (size_t)C_DIM * H_DIM);

  const dim3 blk(256);
  const dim3 gN1(C_DIM / 128, M_ROWS / 128);   // (8, 128)
  const dim3 gN4(H_DIM / 128, M_ROWS / 128);   // (32, 128)

  // --- TimeMix ---
  ln_kernel<<<dim3(M_ROWS / 4), blk, 0, stream>>>(x, ln1_g, ln1_b, B0);
  mix3_kernel<<<dim3(M_ROWS * 128 / 256), blk, 0, stream>>>(B0, amk, amv, amr, B1, B2, B3);
  gemm_nt_kernel<0><<<gN1, blk, 0, stream>>>(B1, wWk, B4, nullptr, nullptr, M_ROWS, C_DIM, C_DIM);
  gemm_nt_kernel<0><<<gN1, blk, 0, stream>>>(B2, wWv, B5, nullptr, nullptr, M_ROWS, C_DIM, C_DIM);
  gemm_nt_kernel<0><<<gN1, blk, 0, stream>>>(B3, wWr, B6, nullptr, nullptr, M_ROWS, C_DIM, C_DIM);
  wkv_kernel<<<dim3(16384 / 64), dim3(64), 0, stream>>>(B4, B5, B6, tdec, tfirst, B1);
  gemm_nt_kernel<2><<<gN1, blk, 0, stream>>>(B1, wWo, d_out, x, nullptr, M_ROWS, C_DIM, C_DIM);

  // --- ChannelMix ---
  ln_kernel<<<dim3(M_ROWS / 4), blk, 0, stream>>>((const float*)d_out, ln2_g, ln2_b, B0);
  mix2_kernel<<<dim3(M_ROWS * 128 / 256), blk, 0, stream>>>(B0, cmk, cmr, B1, B2);
  gemm_nt_kernel<1><<<gN4, blk, 0, stream>>>(B1, wWck, B3, nullptr, nullptr, M_ROWS, H_DIM, C_DIM);
  gemm_nt_kernel<0><<<gN1, blk, 0, stream>>>(B3, wWcv, B1, nullptr, nullptr, M_ROWS, C_DIM, H_DIM);
  gemm_nt_kernel<3><<<gN1, blk, 0, stream>>>(B2, wWcr, d_out, (const float*)d_out, B1,
                                             M_ROWS, C_DIM, C_DIM);
}

// Round 3
// 785.632 us; speedup vs baseline: 1.4182x; 1.3433x over previous
//
#include <hip/hip_runtime.h>

#define T_SEQ 1024
#define C_DIM 1024
#define H_DIM 4096
#define M_ROWS 16384   // P*B*T = 2*8*1024
#define CHUNKS 16
#define CLEN 64        // T_SEQ / CHUNKS

typedef _Float16 f16x8 __attribute__((ext_vector_type(8)));
typedef _Float16 f16x4 __attribute__((ext_vector_type(4)));
typedef float    f32x4 __attribute__((ext_vector_type(4)));

#define AS1 __attribute__((address_space(1)))
#define AS3 __attribute__((address_space(3)))

__device__ __forceinline__ void gload_lds16(const void* g, void* l) {
  __builtin_amdgcn_global_load_lds((const AS1 void*)g, (AS3 void*)l, 16, 0, 0);
}

__device__ __forceinline__ float sigmoidf_(float x) {
  return 1.0f / (1.0f + __expf(-x));
}

// ---------------- weight f32 -> f16 ----------------
__global__ __launch_bounds__(256) void cvt_kernel(const float* __restrict__ in,
                                                  _Float16* __restrict__ out, int n4) {
  int i = blockIdx.x * 256 + threadIdx.x;
  if (i >= n4) return;
  f32x4 v = reinterpret_cast<const f32x4*>(in)[i];
  f16x4 o;
  o[0] = (_Float16)v[0]; o[1] = (_Float16)v[1];
  o[2] = (_Float16)v[2]; o[3] = (_Float16)v[3];
  reinterpret_cast<f16x4*>(out)[i] = o;
}

// ---------------- layernorm: f32 in -> f16 out (one wave per row) ----------------
__global__ __launch_bounds__(256) void ln_kernel(const float* __restrict__ x,
    const float* __restrict__ g, const float* __restrict__ b,
    _Float16* __restrict__ h) {
  const int row  = blockIdx.x * 4 + (threadIdx.x >> 6);
  const int lane = threadIdx.x & 63;
  const f32x4* xr = reinterpret_cast<const f32x4*>(x + (size_t)row * C_DIM);
  f32x4 v[4];
  float s = 0.f, sq = 0.f;
#pragma unroll
  for (int i = 0; i < 4; ++i) {
    v[i] = xr[i * 64 + lane];
#pragma unroll
    for (int j = 0; j < 4; ++j) { s += v[i][j]; sq += v[i][j] * v[i][j]; }
  }
#pragma unroll
  for (int off = 32; off > 0; off >>= 1) {
    s  += __shfl_xor(s, off, 64);
    sq += __shfl_xor(sq, off, 64);
  }
  const float mu   = s * (1.0f / C_DIM);
  const float var  = sq * (1.0f / C_DIM) - mu * mu;
  const float rstd = rsqrtf(var + 1e-5f);
  const f32x4* g4 = reinterpret_cast<const f32x4*>(g);
  const f32x4* b4 = reinterpret_cast<const f32x4*>(b);
  f16x4* h4 = reinterpret_cast<f16x4*>(h + (size_t)row * C_DIM);
#pragma unroll
  for (int i = 0; i < 4; ++i) {
    f32x4 gg = g4[i * 64 + lane];
    f32x4 bb = b4[i * 64 + lane];
    f16x4 o;
#pragma unroll
    for (int j = 0; j < 4; ++j)
      o[j] = (_Float16)((v[i][j] - mu) * rstd * gg[j] + bb[j]);
    h4[i * 64 + lane] = o;
  }
}

// ---------------- time-shift mix, 3 outputs ----------------
__global__ __launch_bounds__(256) void mix3_kernel(const _Float16* __restrict__ h,
    const float* __restrict__ mk, const float* __restrict__ mv, const float* __restrict__ mr,
    _Float16* __restrict__ xk, _Float16* __restrict__ xv, _Float16* __restrict__ xr) {
  const int i  = blockIdx.x * 256 + threadIdx.x;   // [0, M_ROWS*128)
  const int m  = i >> 7;
  const int c0 = (i & 127) << 3;
  const int p  = m >> 13;
  const int t  = m & (T_SEQ - 1);
  const f16x8* h8 = reinterpret_cast<const f16x8*>(h);
  f16x8 hc = h8[i];
  f16x8 hp;
#pragma unroll
  for (int j = 0; j < 8; ++j) hp[j] = (_Float16)0.f;
  if (t) hp = h8[i - 128];
  f16x8 ok, ov, orr;
#pragma unroll
  for (int j = 0; j < 8; ++j) {
    const float hcf = (float)hc[j], hpf = (float)hp[j];
    const float a = mk[p * C_DIM + c0 + j];
    const float c = mv[p * C_DIM + c0 + j];
    const float d = mr[p * C_DIM + c0 + j];
    ok[j]  = (_Float16)(hcf * a + hpf * (1.f - a));
    ov[j]  = (_Float16)(hcf * c + hpf * (1.f - c));
    orr[j] = (_Float16)(hcf * d + hpf * (1.f - d));
  }
  reinterpret_cast<f16x8*>(xk)[i] = ok;
  reinterpret_cast<f16x8*>(xv)[i] = ov;
  reinterpret_cast<f16x8*>(xr)[i] = orr;
}

// ---------------- time-shift mix, 2 outputs ----------------
__global__ __launch_bounds__(256) void mix2_kernel(const _Float16* __restrict__ h,
    const float* __restrict__ mk, const float* __restrict__ mr,
    _Float16* __restrict__ xk, _Float16* __restrict__ xr) {
  const int i  = blockIdx.x * 256 + threadIdx.x;
  const int m  = i >> 7;
  const int c0 = (i & 127) << 3;
  const int p  = m >> 13;
  const int t  = m & (T_SEQ - 1);
  const f16x8* h8 = reinterpret_cast<const f16x8*>(h);
  f16x8 hc = h8[i];
  f16x8 hp;
#pragma unroll
  for (int j = 0; j < 8; ++j) hp[j] = (_Float16)0.f;
  if (t) hp = h8[i - 128];
  f16x8 ok, orr;
#pragma unroll
  for (int j = 0; j < 8; ++j) {
    const float hcf = (float)hc[j], hpf = (float)hp[j];
    const float a = mk[p * C_DIM + c0 + j];
    const float d = mr[p * C_DIM + c0 + j];
    ok[j]  = (_Float16)(hcf * a + hpf * (1.f - a));
    orr[j] = (_Float16)(hcf * d + hpf * (1.f - d));
  }
  reinterpret_cast<f16x8*>(xk)[i] = ok;
  reinterpret_cast<f16x8*>(xr)[i] = orr;
}

// ---------------- WKV parallel chunked scan, fused with a = sigmoid(r)*y -------
// Recurrence per (seq n, channel c):  a_t = e^w a_{t-1} + e^{k_t} v_t,
//                                     b_t = e^w b_{t-1} + e^{k_t}
// y_t = (a_{t-1} + e^{u+k_t} v_t) / (b_{t-1} + e^{u+k_t})
// State kept max-normalized as (A, B, P) meaning (A e^P, B e^P).
// Block: one (seq, 64-channel group); tid = chunk*64 + ch; wave == chunk.
__global__ __launch_bounds__(1024, 1) void wkv_kernel(const _Float16* __restrict__ k,
    const _Float16* __restrict__ v, const _Float16* __restrict__ r,
    const float* __restrict__ td, const float* __restrict__ tf,
    _Float16* __restrict__ a_out) {
  __shared__ float sA[CHUNKS][64];
  __shared__ float sB[CHUNKS][64];
  __shared__ float sP[CHUNKS][64];
  const int tid   = threadIdx.x;
  const int chunk = tid >> 6;
  const int ch    = tid & 63;
  const int n     = blockIdx.x >> 4;     // 16 sequences
  const int cg    = blockIdx.x & 15;     // 16 channel groups of 64
  const int c     = cg * 64 + ch;
  const float w = -__expf(td[c]);
  const float u = tf[c];
  const size_t cbase = (size_t)n * T_SEQ * C_DIM + (size_t)chunk * CLEN * C_DIM + c;

  // ---- phase 1: local chunk scan from empty state (state only) ----
  float aa = 0.f, bb = 0.f, pp = -1e38f;
  for (int s = 0; s < CLEN; ++s) {
    const size_t idx = cbase + (size_t)s * C_DIM;
    const float kk = (float)k[idx];
    const float vv = (float)v[idx];
    const float ww2 = w + pp;
    const float p2  = fmaxf(ww2, kk);
    const float e1b = __expf(ww2 - p2);
    const float e2b = __expf(kk - p2);
    aa = e1b * aa + e2b * vv;
    bb = e1b * bb + e2b;
    pp = p2;
  }
  sA[chunk][ch] = aa; sB[chunk][ch] = bb; sP[chunk][ch] = pp;
  __syncthreads();

  // ---- phase 2: exclusive prefix across chunks (wave 0, one thread/channel) ----
  if (chunk == 0) {
    float pa = 0.f, pb = 0.f, ppr = -1e38f;       // empty prefix
    const float wL = w * (float)CLEN;             // decay over a whole chunk
    for (int j = 0; j < CHUNKS; ++j) {
      const float la = sA[j][ch], lb = sB[j][ch], lp = sP[j][ch];
      sA[j][ch] = pa; sB[j][ch] = pb; sP[j][ch] = ppr;
      const float dp = wL + ppr;
      const float np = fmaxf(dp, lp);
      const float e1 = __expf(dp - np);
      const float e2 = __expf(lp - np);
      pa  = e1 * pa + e2 * la;
      pb  = e1 * pb + e2 * lb;
      ppr = np;
    }
  }
  __syncthreads();

  // ---- phase 3: re-scan chunk from prefix state, emit sigmoid(r)*y ----
  aa = sA[chunk][ch]; bb = sB[chunk][ch]; pp = sP[chunk][ch];
  for (int s = 0; s < CLEN; ++s) {
    const size_t idx = cbase + (size_t)s * C_DIM;
    const float kk = (float)k[idx];
    const float vv = (float)v[idx];
    const float ww = u + kk;
    const float p  = fmaxf(pp, ww);
    const float e1 = __expf(pp - p);
    const float e2 = __expf(ww - p);
    const float yv = __fdividef(e1 * aa + e2 * vv, e1 * bb + e2);
    const float sr = sigmoidf_((float)r[idx]);
    a_out[idx] = (_Float16)(sr * yv);
    const float ww2 = w + pp;
    const float p2  = fmaxf(ww2, kk);
    const float e1b = __expf(ww2 - p2);
    const float e2b = __expf(kk - p2);
    aa = e1b * aa + e2b * vv;
    bb = e1b * bb + e2b;
    pp = p2;
  }
}

// ---------------- GEMM: C[M,N] = A[M,K] * B[N,K]^T  (f16 in, f32 acc) ----------------
// EPI 0: store f16
// EPI 1: store f16(relu(acc)^2)
// EPI 2: store f32 (acc + X)
// EPI 3: store f32 (X + sigmoid(acc) * KV)
template<int EPI>
__global__ __launch_bounds__(256) void gemm_nt_kernel(
    const _Float16* __restrict__ A, const _Float16* __restrict__ B,
    void* __restrict__ Cv, const float* __restrict__ X,
    const _Float16* __restrict__ KV, int M, int N, int K) {
  __shared__ _Float16 lA[128 * 64];
  __shared__ _Float16 lB[128 * 64];
  const int tid  = threadIdx.x;
  const int wave = tid >> 6;
  const int lane = tid & 63;
  const int wr   = wave >> 1;
  const int wc   = wave & 1;

  // XCD-bijective swizzle: XCD (= linear_id % 8) owns a contiguous M chunk,
  // n-fastest within (A panel reuse in L2; B panel streams L2/L3-resident).
  const unsigned nwx = gridDim.x;                 // N/128
  const unsigned per = gridDim.y >> 3;            // m-tiles per XCD (gridDim.y % 8 == 0)
  const unsigned id  = blockIdx.y * nwx + blockIdx.x;
  const unsigned xcd = id & 7;
  const unsigned loc = id >> 3;
  const size_t m0 = (size_t)(xcd * per + loc / nwx) * 128;
  const size_t n0 = (size_t)(loc % nwx) * 128;

  // staging: 16 chunks of 1KB; wave w stages chunks w*4..w*4+3 for A and B.
  // LDS dest is LINEAR (global_load_lds requirement); the T2 st-swizzle is
  // applied by XOR-permuting the SOURCE 16B-slot within each 128B row
  // (involution), and the same XOR on the ds_read side.
  const int srow = lane >> 3;                          // 0..7 (row within chunk)
  const int scol = ((lane & 7) ^ srow) * 8;            // swizzled col (halfs)
  const _Float16* pA[4];
  const _Float16* pB[4];
#pragma unroll
  for (int i = 0; i < 4; ++i) {
    const int chunk = wave * 4 + i;
    pA[i] = A + (m0 + (size_t)(chunk * 8 + srow)) * K + scol;
    pB[i] = B + (n0 + (size_t)(chunk * 8 + srow)) * K + scol;
  }
  const int frow = lane & 15;
  const int fk   = (lane >> 4) * 8;
  const int fxor = (frow & 7) << 3;                    // read-side XOR (halfs)

  const f32x4 zf = {0.f, 0.f, 0.f, 0.f};
  f32x4 acc[4][4];
#pragma unroll
  for (int i = 0; i < 4; ++i)
#pragma unroll
    for (int j = 0; j < 4; ++j) acc[i][j] = zf;

  for (int k0 = 0; k0 < K; k0 += 64) {
#pragma unroll
    for (int i = 0; i < 4; ++i)
      gload_lds16(pA[i] + k0, &lA[(wave * 4 + i) * 512]);
#pragma unroll
    for (int i = 0; i < 4; ++i)
      gload_lds16(pB[i] + k0, &lB[(wave * 4 + i) * 512]);
    __syncthreads();
#pragma unroll
    for (int kk = 0; kk < 64; kk += 32) {
      f16x8 af[4], bf[4];
#pragma unroll
      for (int i = 0; i < 4; ++i)
        af[i] = *reinterpret_cast<const f16x8*>(
            &lA[(wr * 64 + i * 16 + frow) * 64 + ((kk + fk) ^ fxor)]);
#pragma unroll
      for (int j = 0; j < 4; ++j)
        bf[j] = *reinterpret_cast<const f16x8*>(
            &lB[(wc * 64 + j * 16 + frow) * 64 + ((kk + fk) ^ fxor)]);
#pragma unroll
      for (int i = 0; i < 4; ++i)
#pragma unroll
        for (int j = 0; j < 4; ++j)
          acc[i][j] = __builtin_amdgcn_mfma_f32_16x16x32_f16(af[i], bf[j], acc[i][j], 0, 0, 0);
    }
    __syncthreads();
  }

  // epilogue: C/D layout (16x16): col = lane&15, row = (lane>>4)*4 + reg
  const int ecol = lane & 15;
  const int erow = (lane >> 4) * 4;
#pragma unroll
  for (int i = 0; i < 4; ++i)
#pragma unroll
    for (int j = 0; j < 4; ++j) {
      const size_t rbase = m0 + (size_t)(wr * 64 + i * 16 + erow);
      const size_t cc    = n0 + (size_t)(wc * 64 + j * 16 + ecol);
#pragma unroll
      for (int r = 0; r < 4; ++r) {
        const float val = acc[i][j][r];
        const size_t off = (rbase + r) * (size_t)N + cc;
        if constexpr (EPI == 0) {
          ((_Float16*)Cv)[off] = (_Float16)val;
        } else if constexpr (EPI == 1) {
          const float t = fmaxf(val, 0.f);
          ((_Float16*)Cv)[off] = (_Float16)(t * t);
        } else if constexpr (EPI == 2) {
          ((float*)Cv)[off] = val + X[off];
        } else {
          ((float*)Cv)[off] = X[off] + sigmoidf_(val) * (float)KV[off];
        }
      }
    }
}

extern "C" void kernel_launch(void* const* d_in, const int* in_sizes, int n_in,
                              void* d_out, int out_size, void* d_ws, size_t ws_size,
                              hipStream_t stream) {
  const float* x      = (const float*)d_in[0];
  const float* ln1_g  = (const float*)d_in[1];
  const float* ln1_b  = (const float*)d_in[2];
  const float* ln2_g  = (const float*)d_in[3];
  const float* ln2_b  = (const float*)d_in[4];
  const float* tdec   = (const float*)d_in[5];
  const float* tfirst = (const float*)d_in[6];
  const float* amk    = (const float*)d_in[7];
  const float* amv    = (const float*)d_in[8];
  const float* amr    = (const float*)d_in[9];
  const float* Wk     = (const float*)d_in[10];
  const float* Wv     = (const float*)d_in[11];
  const float* Wr     = (const float*)d_in[12];
  const float* Wo     = (const float*)d_in[13];
  const float* cmk    = (const float*)d_in[14];
  const float* cmr    = (const float*)d_in[15];
  const float* Wck    = (const float*)d_in[16];
  const float* Wcr    = (const float*)d_in[17];
  const float* Wcv    = (const float*)d_in[18];

  char* ws = (char*)d_ws;
  const size_t SZ = (size_t)M_ROWS * C_DIM * sizeof(_Float16);  // 32 MiB
  _Float16* B0 = (_Float16*)(ws + 0 * SZ);
  _Float16* B1 = (_Float16*)(ws + 1 * SZ);
  _Float16* B2 = (_Float16*)(ws + 2 * SZ);
  _Float16* B3 = (_Float16*)(ws + 3 * SZ);   // kk spans B3..B6 (128 MiB)
  _Float16* B4 = (_Float16*)(ws + 4 * SZ);
  _Float16* B5 = (_Float16*)(ws + 5 * SZ);
  _Float16* B6 = (_Float16*)(ws + 6 * SZ);
  _Float16* wWk  = (_Float16*)(ws + 7 * SZ);
  _Float16* wWv  = wWk  + (size_t)C_DIM * C_DIM;
  _Float16* wWr  = wWv  + (size_t)C_DIM * C_DIM;
  _Float16* wWo  = wWr  + (size_t)C_DIM * C_DIM;
  _Float16* wWcr = wWo  + (size_t)C_DIM * C_DIM;
  _Float16* wWck = wWcr + (size_t)C_DIM * C_DIM;
  _Float16* wWcv = wWck + (size_t)H_DIM * C_DIM;

  auto cvt = [&](const float* src, _Float16* dst, size_t n) {
    const int n4 = (int)(n / 4);
    cvt_kernel<<<dim3((n4 + 255) / 256), dim3(256), 0, stream>>>(src, dst, n4);
  };
  cvt(Wk,  wWk,  (size_t)C_DIM * C_DIM);
  cvt(Wv,  wWv,  (size_t)C_DIM * C_DIM);
  cvt(Wr,  wWr,  (size_t)C_DIM * C_DIM);
  cvt(Wo,  wWo,  (size_t)C_DIM * C_DIM);
  cvt(Wcr, wWcr, (size_t)C_DIM * C_DIM);
  cvt(Wck, wWck, (size_t)H_DIM * C_DIM);
  cvt(Wcv, wWcv, (size_t)C_DIM * H_DIM);

  const dim3 blk(256);
  const dim3 gN1(C_DIM / 128, M_ROWS / 128);   // (8, 128)
  const dim3 gN4(H_DIM / 128, M_ROWS / 128);   // (32, 128)

  // --- TimeMix ---
  ln_kernel<<<dim3(M_ROWS / 4), blk, 0, stream>>>(x, ln1_g, ln1_b, B0);
  mix3_kernel<<<dim3(M_ROWS * 128 / 256), blk, 0, stream>>>(B0, amk, amv, amr, B1, B2, B3);
  gemm_nt_kernel<0><<<gN1, blk, 0, stream>>>(B1, wWk, B4, nullptr, nullptr, M_ROWS, C_DIM, C_DIM);
  gemm_nt_kernel<0><<<gN1, blk, 0, stream>>>(B2, wWv, B5, nullptr, nullptr, M_ROWS, C_DIM, C_DIM);
  gemm_nt_kernel<0><<<gN1, blk, 0, stream>>>(B3, wWr, B6, nullptr, nullptr, M_ROWS, C_DIM, C_DIM);
  wkv_kernel<<<dim3(256), dim3(1024), 0, stream>>>(B4, B5, B6, tdec, tfirst, B1);
  gemm_nt_kernel<2><<<gN1, blk, 0, stream>>>(B1, wWo, d_out, x, nullptr, M_ROWS, C_DIM, C_DIM);

  // --- ChannelMix ---
  ln_kernel<<<dim3(M_ROWS / 4), blk, 0, stream>>>((const float*)d_out, ln2_g, ln2_b, B0);
  mix2_kernel<<<dim3(M_ROWS * 128 / 256), blk, 0, stream>>>(B0, cmk, cmr, B1, B2);
  gemm_nt_kernel<1><<<gN4, blk, 0, stream>>>(B1, wWck, B3, nullptr, nullptr, M_ROWS, H_DIM, C_DIM);
  gemm_nt_kernel<0><<<gN1, blk, 0, stream>>>(B3, wWcv, B1, nullptr, nullptr, M_ROWS, C_DIM, H_DIM);
  gemm_nt_kernel<3><<<gN1, blk, 0, stream>>>(B2, wWcr, d_out, (const float*)d_out, B1,
                                             M_ROWS, C_DIM, C_DIM);
}

// Round 5
// 680.629 us; speedup vs baseline: 1.6370x; 1.1543x over previous
//
#include <hip/hip_runtime.h>

#define T_SEQ 1024
#define C_DIM 1024
#define H_DIM 4096
#define M_ROWS 16384   // P*B*T = 2*8*1024
#define CHUNKS 16
#define CLEN 64        // T_SEQ / CHUNKS

typedef _Float16 f16x8 __attribute__((ext_vector_type(8)));
typedef _Float16 f16x4 __attribute__((ext_vector_type(4)));
typedef float    f32x4 __attribute__((ext_vector_type(4)));

#define AS1 __attribute__((address_space(1)))
#define AS3 __attribute__((address_space(3)))

__device__ __forceinline__ void gload_lds16(const void* g, void* l) {
  __builtin_amdgcn_global_load_lds((const AS1 void*)g, (AS3 void*)l, 16, 0, 0);
}

__device__ __forceinline__ float sigmoidf_(float x) {
  return 1.0f / (1.0f + __expf(-x));
}

// ---------------- weight f32 -> f16 ----------------
__global__ __launch_bounds__(256) void cvt_kernel(const float* __restrict__ in,
                                                  _Float16* __restrict__ out, int n4) {
  int i = blockIdx.x * 256 + threadIdx.x;
  if (i >= n4) return;
  f32x4 v = reinterpret_cast<const f32x4*>(in)[i];
  f16x4 o;
  o[0] = (_Float16)v[0]; o[1] = (_Float16)v[1];
  o[2] = (_Float16)v[2]; o[3] = (_Float16)v[3];
  reinterpret_cast<f16x4*>(out)[i] = o;
}

// ---------------- layernorm: f32 in -> f16 out (one wave per row) ----------------
__global__ __launch_bounds__(256) void ln_kernel(const float* __restrict__ x,
    const float* __restrict__ g, const float* __restrict__ b,
    _Float16* __restrict__ h) {
  const int row  = blockIdx.x * 4 + (threadIdx.x >> 6);
  const int lane = threadIdx.x & 63;
  const f32x4* xr = reinterpret_cast<const f32x4*>(x + (size_t)row * C_DIM);
  f32x4 v[4];
  float s = 0.f, sq = 0.f;
#pragma unroll
  for (int i = 0; i < 4; ++i) {
    v[i] = xr[i * 64 + lane];
#pragma unroll
    for (int j = 0; j < 4; ++j) { s += v[i][j]; sq += v[i][j] * v[i][j]; }
  }
#pragma unroll
  for (int off = 32; off > 0; off >>= 1) {
    s  += __shfl_xor(s, off, 64);
    sq += __shfl_xor(sq, off, 64);
  }
  const float mu   = s * (1.0f / C_DIM);
  const float var  = sq * (1.0f / C_DIM) - mu * mu;
  const float rstd = rsqrtf(var + 1e-5f);
  const f32x4* g4 = reinterpret_cast<const f32x4*>(g);
  const f32x4* b4 = reinterpret_cast<const f32x4*>(b);
  f16x4* h4 = reinterpret_cast<f16x4*>(h + (size_t)row * C_DIM);
#pragma unroll
  for (int i = 0; i < 4; ++i) {
    f32x4 gg = g4[i * 64 + lane];
    f32x4 bb = b4[i * 64 + lane];
    f16x4 o;
#pragma unroll
    for (int j = 0; j < 4; ++j)
      o[j] = (_Float16)((v[i][j] - mu) * rstd * gg[j] + bb[j]);
    h4[i * 64 + lane] = o;
  }
}

// ---------------- time-shift mix, 3 outputs ----------------
__global__ __launch_bounds__(256) void mix3_kernel(const _Float16* __restrict__ h,
    const float* __restrict__ mk, const float* __restrict__ mv, const float* __restrict__ mr,
    _Float16* __restrict__ xk, _Float16* __restrict__ xv, _Float16* __restrict__ xr) {
  const int i  = blockIdx.x * 256 + threadIdx.x;   // [0, M_ROWS*128)
  const int m  = i >> 7;
  const int c0 = (i & 127) << 3;
  const int p  = m >> 13;
  const int t  = m & (T_SEQ - 1);
  const f16x8* h8 = reinterpret_cast<const f16x8*>(h);
  f16x8 hc = h8[i];
  f16x8 hp;
#pragma unroll
  for (int j = 0; j < 8; ++j) hp[j] = (_Float16)0.f;
  if (t) hp = h8[i - 128];
  f16x8 ok, ov, orr;
#pragma unroll
  for (int j = 0; j < 8; ++j) {
    const float hcf = (float)hc[j], hpf = (float)hp[j];
    const float a = mk[p * C_DIM + c0 + j];
    const float c = mv[p * C_DIM + c0 + j];
    const float d = mr[p * C_DIM + c0 + j];
    ok[j]  = (_Float16)(hcf * a + hpf * (1.f - a));
    ov[j]  = (_Float16)(hcf * c + hpf * (1.f - c));
    orr[j] = (_Float16)(hcf * d + hpf * (1.f - d));
  }
  reinterpret_cast<f16x8*>(xk)[i] = ok;
  reinterpret_cast<f16x8*>(xv)[i] = ov;
  reinterpret_cast<f16x8*>(xr)[i] = orr;
}

// ---------------- time-shift mix, 2 outputs ----------------
__global__ __launch_bounds__(256) void mix2_kernel(const _Float16* __restrict__ h,
    const float* __restrict__ mk, const float* __restrict__ mr,
    _Float16* __restrict__ xk, _Float16* __restrict__ xr) {
  const int i  = blockIdx.x * 256 + threadIdx.x;
  const int m  = i >> 7;
  const int c0 = (i & 127) << 3;
  const int p  = m >> 13;
  const int t  = m & (T_SEQ - 1);
  const f16x8* h8 = reinterpret_cast<const f16x8*>(h);
  f16x8 hc = h8[i];
  f16x8 hp;
#pragma unroll
  for (int j = 0; j < 8; ++j) hp[j] = (_Float16)0.f;
  if (t) hp = h8[i - 128];
  f16x8 ok, orr;
#pragma unroll
  for (int j = 0; j < 8; ++j) {
    const float hcf = (float)hc[j], hpf = (float)hp[j];
    const float a = mk[p * C_DIM + c0 + j];
    const float d = mr[p * C_DIM + c0 + j];
    ok[j]  = (_Float16)(hcf * a + hpf * (1.f - a));
    orr[j] = (_Float16)(hcf * d + hpf * (1.f - d));
  }
  reinterpret_cast<f16x8*>(xk)[i] = ok;
  reinterpret_cast<f16x8*>(xr)[i] = orr;
}

// ---------------- WKV parallel chunked scan, fused with a = sigmoid(r)*y -------
__global__ __launch_bounds__(1024, 1) void wkv_kernel(const _Float16* __restrict__ k,
    const _Float16* __restrict__ v, const _Float16* __restrict__ r,
    const float* __restrict__ td, const float* __restrict__ tf,
    _Float16* __restrict__ a_out) {
  __shared__ float sA[CHUNKS][64];
  __shared__ float sB[CHUNKS][64];
  __shared__ float sP[CHUNKS][64];
  const int tid   = threadIdx.x;
  const int chunk = tid >> 6;
  const int ch    = tid & 63;
  const int n     = blockIdx.x >> 4;     // 16 sequences
  const int cg    = blockIdx.x & 15;     // 16 channel groups of 64
  const int c     = cg * 64 + ch;
  const float w = -__expf(td[c]);
  const float u = tf[c];
  const size_t cbase = (size_t)n * T_SEQ * C_DIM + (size_t)chunk * CLEN * C_DIM + c;

  // ---- phase 1: local chunk scan from empty state (state only) ----
  float aa = 0.f, bb = 0.f, pp = -1e38f;
  for (int s = 0; s < CLEN; ++s) {
    const size_t idx = cbase + (size_t)s * C_DIM;
    const float kk = (float)k[idx];
    const float vv = (float)v[idx];
    const float ww2 = w + pp;
    const float p2  = fmaxf(ww2, kk);
    const float e1b = __expf(ww2 - p2);
    const float e2b = __expf(kk - p2);
    aa = e1b * aa + e2b * vv;
    bb = e1b * bb + e2b;
    pp = p2;
  }
  sA[chunk][ch] = aa; sB[chunk][ch] = bb; sP[chunk][ch] = pp;
  __syncthreads();

  // ---- phase 2: exclusive prefix across chunks ----
  if (chunk == 0) {
    float pa = 0.f, pb = 0.f, ppr = -1e38f;
    const float wL = w * (float)CLEN;
    for (int j = 0; j < CHUNKS; ++j) {
      const float la = sA[j][ch], lb = sB[j][ch], lp = sP[j][ch];
      sA[j][ch] = pa; sB[j][ch] = pb; sP[j][ch] = ppr;
      const float dp = wL + ppr;
      const float np = fmaxf(dp, lp);
      const float e1 = __expf(dp - np);
      const float e2 = __expf(lp - np);
      pa  = e1 * pa + e2 * la;
      pb  = e1 * pb + e2 * lb;
      ppr = np;
    }
  }
  __syncthreads();

  // ---- phase 3: re-scan chunk from prefix state, emit sigmoid(r)*y ----
  aa = sA[chunk][ch]; bb = sB[chunk][ch]; pp = sP[chunk][ch];
  for (int s = 0; s < CLEN; ++s) {
    const size_t idx = cbase + (size_t)s * C_DIM;
    const float kk = (float)k[idx];
    const float vv = (float)v[idx];
    const float ww = u + kk;
    const float p  = fmaxf(pp, ww);
    const float e1 = __expf(pp - p);
    const float e2 = __expf(ww - p);
    const float yv = __fdividef(e1 * aa + e2 * vv, e1 * bb + e2);
    const float sr = sigmoidf_((float)r[idx]);
    a_out[idx] = (_Float16)(sr * yv);
    const float ww2 = w + pp;
    const float p2  = fmaxf(ww2, kk);
    const float e1b = __expf(ww2 - p2);
    const float e2b = __expf(kk - p2);
    aa = e1b * aa + e2b * vv;
    bb = e1b * bb + e2b;
    pp = p2;
  }
}

// ============ 256x256 GEMM, tile-granular counted-vmcnt pipeline ============
// C[M,N] = A[M,K] * B[N,K]^T.  512 threads = 8 waves (2M x 4N), per-wave
// 128x64 output, BK=64, double-buffered LDS (128 KiB).
// Pipeline (wave-uniform wait ledger — reads per wave are divergent across
// half-tiles, so we wait on the WHOLE tile):
//   prologue: stage tile0 -> buf0 (8 loads/wave)
//   iter t:  stage tile t+1 -> buf b^1 (8 loads; buffer's prior readers
//            finished before the end-barrier of iter t-1)
//            s_waitcnt vmcnt(8): tile t landed, tile t+1 stays IN FLIGHT
//            across the whole compute phase (never drain to 0 mid-loop)
//            barrier; 4 quadrant phases {ds_read, lgkmcnt(0), 16 MFMA}; barrier
// T2 swizzle via pre-swizzled global SOURCE (linear LDS dest, rule 21) +
// same XOR on ds_read. T5 setprio around MFMA clusters.
// EPI 0: f16; 1: f16(relu^2); 2: f32 acc+X; 3: f32 X + sigmoid(acc)*KV
#define GBAR() do { __builtin_amdgcn_sched_barrier(0); \
                    __builtin_amdgcn_s_barrier(); \
                    __builtin_amdgcn_sched_barrier(0); } while (0)
#define WVN(n) do { asm volatile("s_waitcnt vmcnt(" #n ")" ::: "memory"); \
                    __builtin_amdgcn_sched_barrier(0); } while (0)
#define WL0()  do { asm volatile("s_waitcnt lgkmcnt(0)" ::: "memory"); \
                    __builtin_amdgcn_sched_barrier(0); } while (0)
#define STAGE(op, SRC, row0, k0, bb) do { \
    _Pragma("unroll") \
    for (int c_ = 0; c_ < 2; ++c_) { \
      gload_lds16((SRC) + (size_t)((row0) + c_ * 64) * K + (k0), \
                  &lds[bb][op][((size_t)((row0) + c_ * 64) << 6) + dbase]); \
    } } while (0)
#define RD_A(mh) do { \
    _Pragma("unroll") for (int i_ = 0; i_ < 4; ++i_) \
    _Pragma("unroll") for (int k_ = 0; k_ < 2; ++k_) \
      af[i_][k_] = *reinterpret_cast<const f16x8*>( \
        &lds[b][0][((wr * 128 + (mh) * 64 + i_ * 16 + frow) << 6) + \
                   (((k_ << 5) + fk) ^ fxorh)]); \
  } while (0)
#define RD_B(nh) do { \
    _Pragma("unroll") for (int j_ = 0; j_ < 2; ++j_) \
    _Pragma("unroll") for (int k_ = 0; k_ < 2; ++k_) \
      bf[j_][k_] = *reinterpret_cast<const f16x8*>( \
        &lds[b][1][((wcn * 64 + (nh) * 32 + j_ * 16 + frow) << 6) + \
                   (((k_ << 5) + fk) ^ fxorh)]); \
  } while (0)
#define MM(mh, nh) do { \
    __builtin_amdgcn_s_setprio(1); \
    _Pragma("unroll") for (int k_ = 0; k_ < 2; ++k_) \
    _Pragma("unroll") for (int i_ = 0; i_ < 4; ++i_) \
    _Pragma("unroll") for (int j_ = 0; j_ < 2; ++j_) \
      acc[(mh) * 4 + i_][(nh) * 2 + j_] = __builtin_amdgcn_mfma_f32_16x16x32_f16( \
        af[i_][k_], bf[j_][k_], acc[(mh) * 4 + i_][(nh) * 2 + j_], 0, 0, 0); \
    __builtin_amdgcn_s_setprio(0); \
  } while (0)

template<int EPI>
__global__ __launch_bounds__(512, 2) void gemm_nt_256(
    const _Float16* __restrict__ A, const _Float16* __restrict__ B,
    void* __restrict__ Cv, const float* __restrict__ X,
    const _Float16* __restrict__ KV, int M, int N, int K) {
  __shared__ _Float16 lds[2][2][256 * 64];
  const int tid  = threadIdx.x;
  const int wave = tid >> 6;
  const int lane = tid & 63;
  const int wr   = wave >> 2;     // 0..1
  const int wcn  = wave & 3;      // 0..3

  // XCD-bijective swizzle: XCD owns contiguous M chunk, n-fastest within.
  const unsigned nwx  = gridDim.x;        // N/256
  const unsigned pery = gridDim.y >> 3;   // m-tiles per XCD
  const unsigned id   = blockIdx.y * nwx + blockIdx.x;
  const unsigned xcd  = id & 7;
  const unsigned loc  = id >> 3;
  const size_t m0 = (size_t)(xcd * pery + loc / nwx) * 256;
  const size_t n0 = (size_t)(loc % nwx) * 256;

  // staging geometry: half-tile = 128 rows x 64 halfs; wave w covers rows
  // {row0 + c*64 + w*8 .. +7}; LDS dest is wave-uniform base + lane*16B.
  const int srow  = tid >> 3;                       // 0..63
  const int scolh = ((tid & 7) ^ (srow & 7)) << 3;  // source-swizzled col (halfs)
  const size_t dbase = (size_t)(srow & ~7) << 6;    // wave-uniform
  const _Float16* sA = A + (m0 + srow) * (size_t)K + scolh;
  const _Float16* sB = B + (n0 + srow) * (size_t)K + scolh;

  // fragment geometry
  const int frow  = lane & 15;
  const int fk    = (lane >> 4) << 3;
  const int fxorh = (frow & 7) << 3;

  f32x4 acc[8][4];
#pragma unroll
  for (int i = 0; i < 8; ++i)
#pragma unroll
    for (int j = 0; j < 4; ++j) acc[i][j] = (f32x4){0.f, 0.f, 0.f, 0.f};

  // prologue: stage tile 0 -> buf 0 (8 loads/wave outstanding)
  STAGE(0, sA, 0, 0, 0); STAGE(0, sA, 128, 0, 0);
  STAGE(1, sB, 0, 0, 0); STAGE(1, sB, 128, 0, 0);

  const int NT = K >> 6;
  for (int t = 0; t < NT; ++t) {
    const int b  = t & 1;
    const int nb = b ^ 1;
    const int k1 = (t + 1) << 6;
    if (t + 1 < NT) {
      // stage tile t+1 into the other buffer; its 8 loads stay in flight
      STAGE(0, sA, 0, k1, nb); STAGE(0, sA, 128, k1, nb);
      STAGE(1, sB, 0, k1, nb); STAGE(1, sB, 128, k1, nb);
      WVN(8);          // tile t's 8 loads landed; t+1's 8 in flight
    } else {
      WVN(0);          // last tile: drain
    }
    GBAR();
    f16x8 af[4][2], bf[2][2];
    RD_A(0); RD_B(0); WL0(); MM(0, 0);
    RD_B(1);          WL0(); MM(0, 1);
    RD_A(1); RD_B(0); WL0(); MM(1, 0);
    RD_B(1);          WL0(); MM(1, 1);
    GBAR();
  }

  // epilogue: C/D layout (16x16): col = lane&15, row = (lane>>4)*4 + reg
  const int ecol  = lane & 15;
  const int erow4 = (lane >> 4) * 4;
#pragma unroll
  for (int mf = 0; mf < 8; ++mf)
#pragma unroll
    for (int nf = 0; nf < 4; ++nf) {
      const size_t rbase = m0 + (size_t)(wr * 128 + mf * 16 + erow4);
      const size_t cc    = n0 + (size_t)(wcn * 64 + nf * 16 + ecol);
#pragma unroll
      for (int r = 0; r < 4; ++r) {
        const float val = acc[mf][nf][r];
        const size_t off = (rbase + r) * (size_t)N + cc;
        if constexpr (EPI == 0) {
          ((_Float16*)Cv)[off] = (_Float16)val;
        } else if constexpr (EPI == 1) {
          const float tq = fmaxf(val, 0.f);
          ((_Float16*)Cv)[off] = (_Float16)(tq * tq);
        } else if constexpr (EPI == 2) {
          ((float*)Cv)[off] = val + X[off];
        } else {
          ((float*)Cv)[off] = X[off] + sigmoidf_(val) * (float)KV[off];
        }
      }
    }
}

extern "C" void kernel_launch(void* const* d_in, const int* in_sizes, int n_in,
                              void* d_out, int out_size, void* d_ws, size_t ws_size,
                              hipStream_t stream) {
  const float* x      = (const float*)d_in[0];
  const float* ln1_g  = (const float*)d_in[1];
  const float* ln1_b  = (const float*)d_in[2];
  const float* ln2_g  = (const float*)d_in[3];
  const float* ln2_b  = (const float*)d_in[4];
  const float* tdec   = (const float*)d_in[5];
  const float* tfirst = (const float*)d_in[6];
  const float* amk    = (const float*)d_in[7];
  const float* amv    = (const float*)d_in[8];
  const float* amr    = (const float*)d_in[9];
  const float* Wk     = (const float*)d_in[10];
  const float* Wv     = (const float*)d_in[11];
  const float* Wr     = (const float*)d_in[12];
  const float* Wo     = (const float*)d_in[13];
  const float* cmk    = (const float*)d_in[14];
  const float* cmr    = (const float*)d_in[15];
  const float* Wck    = (const float*)d_in[16];
  const float* Wcr    = (const float*)d_in[17];
  const float* Wcv    = (const float*)d_in[18];

  char* ws = (char*)d_ws;
  const size_t SZ = (size_t)M_ROWS * C_DIM * sizeof(_Float16);  // 32 MiB
  _Float16* B0 = (_Float16*)(ws + 0 * SZ);
  _Float16* B1 = (_Float16*)(ws + 1 * SZ);
  _Float16* B2 = (_Float16*)(ws + 2 * SZ);
  _Float16* B3 = (_Float16*)(ws + 3 * SZ);   // kk spans B3..B6 (128 MiB)
  _Float16* B4 = (_Float16*)(ws + 4 * SZ);
  _Float16* B5 = (_Float16*)(ws + 5 * SZ);
  _Float16* B6 = (_Float16*)(ws + 6 * SZ);
  _Float16* wWk  = (_Float16*)(ws + 7 * SZ);
  _Float16* wWv  = wWk  + (size_t)C_DIM * C_DIM;
  _Float16* wWr  = wWv  + (size_t)C_DIM * C_DIM;
  _Float16* wWo  = wWr  + (size_t)C_DIM * C_DIM;
  _Float16* wWcr = wWo  + (size_t)C_DIM * C_DIM;
  _Float16* wWck = wWcr + (size_t)C_DIM * C_DIM;
  _Float16* wWcv = wWck + (size_t)H_DIM * C_DIM;

  auto cvt = [&](const float* src, _Float16* dst, size_t n) {
    const int n4 = (int)(n / 4);
    cvt_kernel<<<dim3((n4 + 255) / 256), dim3(256), 0, stream>>>(src, dst, n4);
  };
  cvt(Wk,  wWk,  (size_t)C_DIM * C_DIM);
  cvt(Wv,  wWv,  (size_t)C_DIM * C_DIM);
  cvt(Wr,  wWr,  (size_t)C_DIM * C_DIM);
  cvt(Wo,  wWo,  (size_t)C_DIM * C_DIM);
  cvt(Wcr, wWcr, (size_t)C_DIM * C_DIM);
  cvt(Wck, wWck, (size_t)H_DIM * C_DIM);
  cvt(Wcv, wWcv, (size_t)C_DIM * H_DIM);

  const dim3 blk(256);
  const dim3 gblk(512);
  const dim3 gN1(C_DIM / 256, M_ROWS / 256);   // (4, 64)
  const dim3 gN4(H_DIM / 256, M_ROWS / 256);   // (16, 64)

  // --- TimeMix ---
  ln_kernel<<<dim3(M_ROWS / 4), blk, 0, stream>>>(x, ln1_g, ln1_b, B0);
  mix3_kernel<<<dim3(M_ROWS * 128 / 256), blk, 0, stream>>>(B0, amk, amv, amr, B1, B2, B3);
  gemm_nt_256<0><<<gN1, gblk, 0, stream>>>(B1, wWk, B4, nullptr, nullptr, M_ROWS, C_DIM, C_DIM);
  gemm_nt_256<0><<<gN1, gblk, 0, stream>>>(B2, wWv, B5, nullptr, nullptr, M_ROWS, C_DIM, C_DIM);
  gemm_nt_256<0><<<gN1, gblk, 0, stream>>>(B3, wWr, B6, nullptr, nullptr, M_ROWS, C_DIM, C_DIM);
  wkv_kernel<<<dim3(256), dim3(1024), 0, stream>>>(B4, B5, B6, tdec, tfirst, B1);
  gemm_nt_256<2><<<gN1, gblk, 0, stream>>>(B1, wWo, d_out, x, nullptr, M_ROWS, C_DIM, C_DIM);

  // --- ChannelMix ---
  ln_kernel<<<dim3(M_ROWS / 4), blk, 0, stream>>>((const float*)d_out, ln2_g, ln2_b, B0);
  mix2_kernel<<<dim3(M_ROWS * 128 / 256), blk, 0, stream>>>(B0, cmk, cmr, B1, B2);
  gemm_nt_256<1><<<gN4, gblk, 0, stream>>>(B1, wWck, B3, nullptr, nullptr, M_ROWS, H_DIM, C_DIM);
  gemm_nt_256<0><<<gN1, gblk, 0, stream>>>(B3, wWcv, B1, nullptr, nullptr, M_ROWS, C_DIM, H_DIM);
  gemm_nt_256<3><<<gN1, gblk, 0, stream>>>(B2, wWcr, d_out, (const float*)d_out, B1,
                                           M_ROWS, C_DIM, C_DIM);
}

// Round 6
// 668.557 us; speedup vs baseline: 1.6666x; 1.0181x over previous
//
#include <hip/hip_runtime.h>

#define T_SEQ 1024
#define C_DIM 1024
#define H_DIM 4096
#define M_ROWS 16384   // P*B*T = 2*8*1024
#define CHUNKS 16
#define CLEN 64        // T_SEQ / CHUNKS

typedef _Float16 f16x8 __attribute__((ext_vector_type(8)));
typedef _Float16 f16x4 __attribute__((ext_vector_type(4)));
typedef float    f32x4 __attribute__((ext_vector_type(4)));

#define AS1 __attribute__((address_space(1)))
#define AS3 __attribute__((address_space(3)))

__device__ __forceinline__ void gload_lds16(const void* g, void* l) {
  __builtin_amdgcn_global_load_lds((const AS1 void*)g, (AS3 void*)l, 16, 0, 0);
}

__device__ __forceinline__ float sigmoidf_(float x) {
  return 1.0f / (1.0f + __expf(-x));
}

// ---------------- fused weight f32 -> f16 (all 7 weights, one launch) --------
struct CvtArgs {
  const float* src[7];
  _Float16*    dst[7];
  int n4[7];       // elements/4 per source
  int start[8];    // block-range prefix
};

__global__ __launch_bounds__(256) void cvt_all_kernel(CvtArgs a) {
  const int bid = blockIdx.x;
  int s = 0;
#pragma unroll
  for (int j = 0; j < 7; ++j) s += (bid >= a.start[j + 1]) ? 1 : 0;
  const int i = (bid - a.start[s]) * 256 + threadIdx.x;
  if (i >= a.n4[s]) return;
  f32x4 v = reinterpret_cast<const f32x4*>(a.src[s])[i];
  f16x4 o;
  o[0] = (_Float16)v[0]; o[1] = (_Float16)v[1];
  o[2] = (_Float16)v[2]; o[3] = (_Float16)v[3];
  reinterpret_cast<f16x4*>(a.dst[s])[i] = o;
}

// ---------------- layernorm: f32 in -> f16 out (one wave per row) ----------------
__global__ __launch_bounds__(256) void ln_kernel(const float* __restrict__ x,
    const float* __restrict__ g, const float* __restrict__ b,
    _Float16* __restrict__ h) {
  const int row  = blockIdx.x * 4 + (threadIdx.x >> 6);
  const int lane = threadIdx.x & 63;
  const f32x4* xr = reinterpret_cast<const f32x4*>(x + (size_t)row * C_DIM);
  f32x4 v[4];
  float s = 0.f, sq = 0.f;
#pragma unroll
  for (int i = 0; i < 4; ++i) {
    v[i] = xr[i * 64 + lane];
#pragma unroll
    for (int j = 0; j < 4; ++j) { s += v[i][j]; sq += v[i][j] * v[i][j]; }
  }
#pragma unroll
  for (int off = 32; off > 0; off >>= 1) {
    s  += __shfl_xor(s, off, 64);
    sq += __shfl_xor(sq, off, 64);
  }
  const float mu   = s * (1.0f / C_DIM);
  const float var  = sq * (1.0f / C_DIM) - mu * mu;
  const float rstd = rsqrtf(var + 1e-5f);
  const f32x4* g4 = reinterpret_cast<const f32x4*>(g);
  const f32x4* b4 = reinterpret_cast<const f32x4*>(b);
  f16x4* h4 = reinterpret_cast<f16x4*>(h + (size_t)row * C_DIM);
#pragma unroll
  for (int i = 0; i < 4; ++i) {
    f32x4 gg = g4[i * 64 + lane];
    f32x4 bb = b4[i * 64 + lane];
    f16x4 o;
#pragma unroll
    for (int j = 0; j < 4; ++j)
      o[j] = (_Float16)((v[i][j] - mu) * rstd * gg[j] + bb[j]);
    h4[i * 64 + lane] = o;
  }
}

// ---------------- time-shift mix, 3 outputs ----------------
__global__ __launch_bounds__(256) void mix3_kernel(const _Float16* __restrict__ h,
    const float* __restrict__ mk, const float* __restrict__ mv, const float* __restrict__ mr,
    _Float16* __restrict__ xk, _Float16* __restrict__ xv, _Float16* __restrict__ xr) {
  const int i  = blockIdx.x * 256 + threadIdx.x;   // [0, M_ROWS*128)
  const int m  = i >> 7;
  const int c0 = (i & 127) << 3;
  const int p  = m >> 13;
  const int t  = m & (T_SEQ - 1);
  const f16x8* h8 = reinterpret_cast<const f16x8*>(h);
  f16x8 hc = h8[i];
  f16x8 hp;
#pragma unroll
  for (int j = 0; j < 8; ++j) hp[j] = (_Float16)0.f;
  if (t) hp = h8[i - 128];
  f16x8 ok, ov, orr;
#pragma unroll
  for (int j = 0; j < 8; ++j) {
    const float hcf = (float)hc[j], hpf = (float)hp[j];
    const float a = mk[p * C_DIM + c0 + j];
    const float c = mv[p * C_DIM + c0 + j];
    const float d = mr[p * C_DIM + c0 + j];
    ok[j]  = (_Float16)(hcf * a + hpf * (1.f - a));
    ov[j]  = (_Float16)(hcf * c + hpf * (1.f - c));
    orr[j] = (_Float16)(hcf * d + hpf * (1.f - d));
  }
  reinterpret_cast<f16x8*>(xk)[i] = ok;
  reinterpret_cast<f16x8*>(xv)[i] = ov;
  reinterpret_cast<f16x8*>(xr)[i] = orr;
}

// ---------------- time-shift mix, 2 outputs ----------------
__global__ __launch_bounds__(256) void mix2_kernel(const _Float16* __restrict__ h,
    const float* __restrict__ mk, const float* __restrict__ mr,
    _Float16* __restrict__ xk, _Float16* __restrict__ xr) {
  const int i  = blockIdx.x * 256 + threadIdx.x;
  const int m  = i >> 7;
  const int c0 = (i & 127) << 3;
  const int p  = m >> 13;
  const int t  = m & (T_SEQ - 1);
  const f16x8* h8 = reinterpret_cast<const f16x8*>(h);
  f16x8 hc = h8[i];
  f16x8 hp;
#pragma unroll
  for (int j = 0; j < 8; ++j) hp[j] = (_Float16)0.f;
  if (t) hp = h8[i - 128];
  f16x8 ok, orr;
#pragma unroll
  for (int j = 0; j < 8; ++j) {
    const float hcf = (float)hc[j], hpf = (float)hp[j];
    const float a = mk[p * C_DIM + c0 + j];
    const float d = mr[p * C_DIM + c0 + j];
    ok[j]  = (_Float16)(hcf * a + hpf * (1.f - a));
    orr[j] = (_Float16)(hcf * d + hpf * (1.f - d));
  }
  reinterpret_cast<f16x8*>(xk)[i] = ok;
  reinterpret_cast<f16x8*>(xr)[i] = orr;
}

// ---------------- WKV parallel chunked scan, fused with a = sigmoid(r)*y -------
__global__ __launch_bounds__(1024, 1) void wkv_kernel(const _Float16* __restrict__ k,
    const _Float16* __restrict__ v, const _Float16* __restrict__ r,
    const float* __restrict__ td, const float* __restrict__ tf,
    _Float16* __restrict__ a_out) {
  __shared__ float sA[CHUNKS][64];
  __shared__ float sB[CHUNKS][64];
  __shared__ float sP[CHUNKS][64];
  const int tid   = threadIdx.x;
  const int chunk = tid >> 6;
  const int ch    = tid & 63;
  const int n     = blockIdx.x >> 4;     // 16 sequences
  const int cg    = blockIdx.x & 15;     // 16 channel groups of 64
  const int c     = cg * 64 + ch;
  const float w = -__expf(td[c]);
  const float u = tf[c];
  const size_t cbase = (size_t)n * T_SEQ * C_DIM + (size_t)chunk * CLEN * C_DIM + c;

  // ---- phase 1: local chunk scan from empty state (state only) ----
  float aa = 0.f, bb = 0.f, pp = -1e38f;
  for (int s = 0; s < CLEN; ++s) {
    const size_t idx = cbase + (size_t)s * C_DIM;
    const float kk = (float)k[idx];
    const float vv = (float)v[idx];
    const float ww2 = w + pp;
    const float p2  = fmaxf(ww2, kk);
    const float e1b = __expf(ww2 - p2);
    const float e2b = __expf(kk - p2);
    aa = e1b * aa + e2b * vv;
    bb = e1b * bb + e2b;
    pp = p2;
  }
  sA[chunk][ch] = aa; sB[chunk][ch] = bb; sP[chunk][ch] = pp;
  __syncthreads();

  // ---- phase 2: exclusive prefix across chunks ----
  if (chunk == 0) {
    float pa = 0.f, pb = 0.f, ppr = -1e38f;
    const float wL = w * (float)CLEN;
    for (int j = 0; j < CHUNKS; ++j) {
      const float la = sA[j][ch], lb = sB[j][ch], lp = sP[j][ch];
      sA[j][ch] = pa; sB[j][ch] = pb; sP[j][ch] = ppr;
      const float dp = wL + ppr;
      const float np = fmaxf(dp, lp);
      const float e1 = __expf(dp - np);
      const float e2 = __expf(lp - np);
      pa  = e1 * pa + e2 * la;
      pb  = e1 * pb + e2 * lb;
      ppr = np;
    }
  }
  __syncthreads();

  // ---- phase 3: re-scan chunk from prefix state, emit sigmoid(r)*y ----
  aa = sA[chunk][ch]; bb = sB[chunk][ch]; pp = sP[chunk][ch];
  for (int s = 0; s < CLEN; ++s) {
    const size_t idx = cbase + (size_t)s * C_DIM;
    const float kk = (float)k[idx];
    const float vv = (float)v[idx];
    const float ww = u + kk;
    const float p  = fmaxf(pp, ww);
    const float e1 = __expf(pp - p);
    const float e2 = __expf(ww - p);
    const float yv = __fdividef(e1 * aa + e2 * vv, e1 * bb + e2);
    const float sr = sigmoidf_((float)r[idx]);
    a_out[idx] = (_Float16)(sr * yv);
    const float ww2 = w + pp;
    const float p2  = fmaxf(ww2, kk);
    const float e1b = __expf(ww2 - p2);
    const float e2b = __expf(kk - p2);
    aa = e1b * aa + e2b * vv;
    bb = e1b * bb + e2b;
    pp = p2;
  }
}

// ============ 256x256 GEMM, tile-granular counted-vmcnt pipeline ============
// C[M,N] = A[M,K] * B[N,K]^T.  512 threads = 8 waves (2M x 4N), per-wave
// 128x64 output, BK=64, double-buffered LDS (128 KiB).
// Per K-tile (wave-uniform wait ledger):
//   stage tile t+1 -> buf b^1 (8 gload_lds); s_waitcnt vmcnt(8) (tile t
//   landed, t+1 stays in flight across compute); barrier.
//   Compute (24 ds_read_b128, the data minimum):
//     G1 = a0[4][2] + bf[4][2] (16 reads) | G2 = a1[4][2] (8 reads)
//     lgkmcnt(8) -> 32 MFMA on a0 x bf (hides G2 latency)
//     lgkmcnt(0) -> 32 MFMA on a1 x bf
//   barrier.
// T2 swizzle via pre-swizzled global SOURCE (linear LDS dest, rule 21) +
// same XOR on ds_read. T5 setprio around MFMA clusters.
// EPI 0: f16; 1: f16(relu^2); 2: f32 acc+X; 3: f32 X + sigmoid(acc)*KV
#define GBAR() do { __builtin_amdgcn_sched_barrier(0); \
                    __builtin_amdgcn_s_barrier(); \
                    __builtin_amdgcn_sched_barrier(0); } while (0)
#define WVN(n) do { asm volatile("s_waitcnt vmcnt(" #n ")" ::: "memory"); \
                    __builtin_amdgcn_sched_barrier(0); } while (0)
#define WLN(n) do { asm volatile("s_waitcnt lgkmcnt(" #n ")" ::: "memory"); \
                    __builtin_amdgcn_sched_barrier(0); } while (0)
#define SCHED() __builtin_amdgcn_sched_barrier(0)
#define STAGE(op, SRC, row0, k0, bb) do { \
    _Pragma("unroll") \
    for (int c_ = 0; c_ < 2; ++c_) { \
      gload_lds16((SRC) + (size_t)((row0) + c_ * 64) * K + (k0), \
                  &lds[bb][op][((size_t)((row0) + c_ * 64) << 6) + dbase]); \
    } } while (0)
#define RD_AH(dst, mh) do { \
    _Pragma("unroll") for (int i_ = 0; i_ < 4; ++i_) \
    _Pragma("unroll") for (int k_ = 0; k_ < 2; ++k_) \
      dst[i_][k_] = *reinterpret_cast<const f16x8*>( \
        &lds[b][0][((wr * 128 + (mh) * 64 + i_ * 16 + frow) << 6) + \
                   (((k_ << 5) + fk) ^ fxorh)]); \
  } while (0)
#define RD_BALL() do { \
    _Pragma("unroll") for (int j_ = 0; j_ < 4; ++j_) \
    _Pragma("unroll") for (int k_ = 0; k_ < 2; ++k_) \
      bf[j_][k_] = *reinterpret_cast<const f16x8*>( \
        &lds[b][1][((wcn * 64 + j_ * 16 + frow) << 6) + \
                   (((k_ << 5) + fk) ^ fxorh)]); \
  } while (0)
#define MM32(src, mh) do { \
    __builtin_amdgcn_s_setprio(1); \
    _Pragma("unroll") for (int k_ = 0; k_ < 2; ++k_) \
    _Pragma("unroll") for (int i_ = 0; i_ < 4; ++i_) \
    _Pragma("unroll") for (int j_ = 0; j_ < 4; ++j_) \
      acc[(mh) * 4 + i_][j_] = __builtin_amdgcn_mfma_f32_16x16x32_f16( \
        src[i_][k_], bf[j_][k_], acc[(mh) * 4 + i_][j_], 0, 0, 0); \
    __builtin_amdgcn_s_setprio(0); \
  } while (0)

template<int EPI>
__global__ __launch_bounds__(512, 2) void gemm_nt_256(
    const _Float16* __restrict__ A, const _Float16* __restrict__ B,
    void* __restrict__ Cv, const float* __restrict__ X,
    const _Float16* __restrict__ KV, int M, int N, int K) {
  __shared__ _Float16 lds[2][2][256 * 64];
  const int tid  = threadIdx.x;
  const int wave = tid >> 6;
  const int lane = tid & 63;
  const int wr   = wave >> 2;     // 0..1
  const int wcn  = wave & 3;      // 0..3

  // XCD-bijective swizzle: XCD owns contiguous M chunk, n-fastest within.
  const unsigned nwx  = gridDim.x;        // N/256
  const unsigned pery = gridDim.y >> 3;   // m-tiles per XCD
  const unsigned id   = blockIdx.y * nwx + blockIdx.x;
  const unsigned xcd  = id & 7;
  const unsigned loc  = id >> 3;
  const size_t m0 = (size_t)(xcd * pery + loc / nwx) * 256;
  const size_t n0 = (size_t)(loc % nwx) * 256;

  // staging geometry: half-tile = 128 rows x 64 halfs; wave w covers rows
  // {row0 + c*64 + w*8 .. +7}; LDS dest is wave-uniform base + lane*16B.
  const int srow  = tid >> 3;                       // 0..63
  const int scolh = ((tid & 7) ^ (srow & 7)) << 3;  // source-swizzled col (halfs)
  const size_t dbase = (size_t)(srow & ~7) << 6;    // wave-uniform
  const _Float16* sA = A + (m0 + srow) * (size_t)K + scolh;
  const _Float16* sB = B + (n0 + srow) * (size_t)K + scolh;

  // fragment geometry
  const int frow  = lane & 15;
  const int fk    = (lane >> 4) << 3;
  const int fxorh = (frow & 7) << 3;

  f32x4 acc[8][4];
#pragma unroll
  for (int i = 0; i < 8; ++i)
#pragma unroll
    for (int j = 0; j < 4; ++j) acc[i][j] = (f32x4){0.f, 0.f, 0.f, 0.f};

  // prologue: stage tile 0 -> buf 0 (8 loads/wave outstanding)
  STAGE(0, sA, 0, 0, 0); STAGE(0, sA, 128, 0, 0);
  STAGE(1, sB, 0, 0, 0); STAGE(1, sB, 128, 0, 0);

  const int NT = K >> 6;
  for (int t = 0; t < NT; ++t) {
    const int b  = t & 1;
    const int nb = b ^ 1;
    const int k1 = (t + 1) << 6;
    if (t + 1 < NT) {
      // stage tile t+1 into the other buffer; its 8 loads stay in flight
      STAGE(0, sA, 0, k1, nb); STAGE(0, sA, 128, k1, nb);
      STAGE(1, sB, 0, k1, nb); STAGE(1, sB, 128, k1, nb);
      WVN(8);          // tile t's 8 loads landed; t+1's 8 in flight
    } else {
      WVN(0);          // last tile: drain
    }
    GBAR();
    f16x8 a0[4][2], a1[4][2], bf[4][2];
    RD_AH(a0, 0); RD_BALL();   // G1: 16 reads
    SCHED();
    RD_AH(a1, 1);              // G2: 8 reads, stays outstanding
    WLN(8);                    // G1 landed, G2 in flight
    MM32(a0, 0);               // 32 MFMA hide G2 latency
    WLN(0);                    // G2 landed
    MM32(a1, 1);
    GBAR();
  }

  // epilogue: C/D layout (16x16): col = lane&15, row = (lane>>4)*4 + reg
  const int ecol  = lane & 15;
  const int erow4 = (lane >> 4) * 4;
#pragma unroll
  for (int mf = 0; mf < 8; ++mf)
#pragma unroll
    for (int nf = 0; nf < 4; ++nf) {
      const size_t rbase = m0 + (size_t)(wr * 128 + mf * 16 + erow4);
      const size_t cc    = n0 + (size_t)(wcn * 64 + nf * 16 + ecol);
#pragma unroll
      for (int r = 0; r < 4; ++r) {
        const float val = acc[mf][nf][r];
        const size_t off = (rbase + r) * (size_t)N + cc;
        if constexpr (EPI == 0) {
          ((_Float16*)Cv)[off] = (_Float16)val;
        } else if constexpr (EPI == 1) {
          const float tq = fmaxf(val, 0.f);
          ((_Float16*)Cv)[off] = (_Float16)(tq * tq);
        } else if constexpr (EPI == 2) {
          ((float*)Cv)[off] = val + X[off];
        } else {
          ((float*)Cv)[off] = X[off] + sigmoidf_(val) * (float)KV[off];
        }
      }
    }
}

extern "C" void kernel_launch(void* const* d_in, const int* in_sizes, int n_in,
                              void* d_out, int out_size, void* d_ws, size_t ws_size,
                              hipStream_t stream) {
  const float* x      = (const float*)d_in[0];
  const float* ln1_g  = (const float*)d_in[1];
  const float* ln1_b  = (const float*)d_in[2];
  const float* ln2_g  = (const float*)d_in[3];
  const float* ln2_b  = (const float*)d_in[4];
  const float* tdec   = (const float*)d_in[5];
  const float* tfirst = (const float*)d_in[6];
  const float* amk    = (const float*)d_in[7];
  const float* amv    = (const float*)d_in[8];
  const float* amr    = (const float*)d_in[9];
  const float* Wk     = (const float*)d_in[10];
  const float* Wv     = (const float*)d_in[11];
  const float* Wr     = (const float*)d_in[12];
  const float* Wo     = (const float*)d_in[13];
  const float* cmk    = (const float*)d_in[14];
  const float* cmr    = (const float*)d_in[15];
  const float* Wck    = (const float*)d_in[16];
  const float* Wcr    = (const float*)d_in[17];
  const float* Wcv    = (const float*)d_in[18];

  char* ws = (char*)d_ws;
  const size_t SZ = (size_t)M_ROWS * C_DIM * sizeof(_Float16);  // 32 MiB
  _Float16* B0 = (_Float16*)(ws + 0 * SZ);
  _Float16* B1 = (_Float16*)(ws + 1 * SZ);
  _Float16* B2 = (_Float16*)(ws + 2 * SZ);
  _Float16* B3 = (_Float16*)(ws + 3 * SZ);   // kk spans B3..B6 (128 MiB)
  _Float16* B4 = (_Float16*)(ws + 4 * SZ);
  _Float16* B5 = (_Float16*)(ws + 5 * SZ);
  _Float16* B6 = (_Float16*)(ws + 6 * SZ);
  _Float16* wWk  = (_Float16*)(ws + 7 * SZ);
  _Float16* wWv  = wWk  + (size_t)C_DIM * C_DIM;
  _Float16* wWr  = wWv  + (size_t)C_DIM * C_DIM;
  _Float16* wWo  = wWr  + (size_t)C_DIM * C_DIM;
  _Float16* wWcr = wWo  + (size_t)C_DIM * C_DIM;
  _Float16* wWck = wWcr + (size_t)C_DIM * C_DIM;
  _Float16* wWcv = wWck + (size_t)H_DIM * C_DIM;

  // fused weight cast: one launch for all 7 weights
  {
    CvtArgs a;
    const float* srcs[7] = {Wk, Wv, Wr, Wo, Wcr, Wck, Wcv};
    _Float16*    dsts[7] = {wWk, wWv, wWr, wWo, wWcr, wWck, wWcv};
    const size_t ns[7]   = {(size_t)C_DIM * C_DIM, (size_t)C_DIM * C_DIM,
                            (size_t)C_DIM * C_DIM, (size_t)C_DIM * C_DIM,
                            (size_t)C_DIM * C_DIM, (size_t)H_DIM * C_DIM,
                            (size_t)C_DIM * H_DIM};
    int st = 0;
    for (int j = 0; j < 7; ++j) {
      a.src[j] = srcs[j]; a.dst[j] = dsts[j];
      a.n4[j] = (int)(ns[j] / 4);
      a.start[j] = st;
      st += (a.n4[j] + 255) / 256;
    }
    a.start[7] = st;
    cvt_all_kernel<<<dim3(st), dim3(256), 0, stream>>>(a);
  }

  const dim3 blk(256);
  const dim3 gblk(512);
  const dim3 gN1(C_DIM / 256, M_ROWS / 256);   // (4, 64)
  const dim3 gN4(H_DIM / 256, M_ROWS / 256);   // (16, 64)

  // --- TimeMix ---
  ln_kernel<<<dim3(M_ROWS / 4), blk, 0, stream>>>(x, ln1_g, ln1_b, B0);
  mix3_kernel<<<dim3(M_ROWS * 128 / 256), blk, 0, stream>>>(B0, amk, amv, amr, B1, B2, B3);
  gemm_nt_256<0><<<gN1, gblk, 0, stream>>>(B1, wWk, B4, nullptr, nullptr, M_ROWS, C_DIM, C_DIM);
  gemm_nt_256<0><<<gN1, gblk, 0, stream>>>(B2, wWv, B5, nullptr, nullptr, M_ROWS, C_DIM, C_DIM);
  gemm_nt_256<0><<<gN1, gblk, 0, stream>>>(B3, wWr, B6, nullptr, nullptr, M_ROWS, C_DIM, C_DIM);
  wkv_kernel<<<dim3(256), dim3(1024), 0, stream>>>(B4, B5, B6, tdec, tfirst, B1);
  gemm_nt_256<2><<<gN1, gblk, 0, stream>>>(B1, wWo, d_out, x, nullptr, M_ROWS, C_DIM, C_DIM);

  // --- ChannelMix ---
  ln_kernel<<<dim3(M_ROWS / 4), blk, 0, stream>>>((const float*)d_out, ln2_g, ln2_b, B0);
  mix2_kernel<<<dim3(M_ROWS * 128 / 256), blk, 0, stream>>>(B0, cmk, cmr, B1, B2);
  gemm_nt_256<1><<<gN4, gblk, 0, stream>>>(B1, wWck, B3, nullptr, nullptr, M_ROWS, H_DIM, C_DIM);
  gemm_nt_256<0><<<gN1, gblk, 0, stream>>>(B3, wWcv, B1, nullptr, nullptr, M_ROWS, C_DIM, H_DIM);
  gemm_nt_256<3><<<gN1, gblk, 0, stream>>>(B2, wWcr, d_out, (const float*)d_out, B1,
                                           M_ROWS, C_DIM, C_DIM);
}

// Round 7
// 659.036 us; speedup vs baseline: 1.6907x; 1.0144x over previous
//
#include <hip/hip_runtime.h>

#define T_SEQ 1024
#define C_DIM 1024
#define H_DIM 4096
#define M_ROWS 16384   // P*B*T = 2*8*1024
#define CHUNKS 16
#define CLEN 64        // T_SEQ / CHUNKS

typedef _Float16 f16x8 __attribute__((ext_vector_type(8)));
typedef _Float16 f16x4 __attribute__((ext_vector_type(4)));
typedef float    f32x4 __attribute__((ext_vector_type(4)));

#define AS1 __attribute__((address_space(1)))
#define AS3 __attribute__((address_space(3)))

__device__ __forceinline__ void gload_lds16(const void* g, void* l) {
  __builtin_amdgcn_global_load_lds((const AS1 void*)g, (AS3 void*)l, 16, 0, 0);
}

__device__ __forceinline__ float sigmoidf_(float x) {
  return 1.0f / (1.0f + __expf(-x));
}

// ---------------- fused weight f32 -> f16 (all 7 weights, one launch) --------
struct CvtArgs {
  const float* src[7];
  _Float16*    dst[7];
  int n4[7];       // elements/4 per source
  int start[8];    // block-range prefix
};

__global__ __launch_bounds__(256) void cvt_all_kernel(CvtArgs a) {
  const int bid = blockIdx.x;
  int s = 0;
#pragma unroll
  for (int j = 0; j < 7; ++j) s += (bid >= a.start[j + 1]) ? 1 : 0;
  const int i = (bid - a.start[s]) * 256 + threadIdx.x;
  if (i >= a.n4[s]) return;
  f32x4 v = reinterpret_cast<const f32x4*>(a.src[s])[i];
  f16x4 o;
  o[0] = (_Float16)v[0]; o[1] = (_Float16)v[1];
  o[2] = (_Float16)v[2]; o[3] = (_Float16)v[3];
  reinterpret_cast<f16x4*>(a.dst[s])[i] = o;
}

// ---------------- layernorm: f32 in -> f16 out (one wave per row) ----------------
__global__ __launch_bounds__(256) void ln_kernel(const float* __restrict__ x,
    const float* __restrict__ g, const float* __restrict__ b,
    _Float16* __restrict__ h) {
  const int row  = blockIdx.x * 4 + (threadIdx.x >> 6);
  const int lane = threadIdx.x & 63;
  const f32x4* xr = reinterpret_cast<const f32x4*>(x + (size_t)row * C_DIM);
  f32x4 v[4];
  float s = 0.f, sq = 0.f;
#pragma unroll
  for (int i = 0; i < 4; ++i) {
    v[i] = xr[i * 64 + lane];
#pragma unroll
    for (int j = 0; j < 4; ++j) { s += v[i][j]; sq += v[i][j] * v[i][j]; }
  }
#pragma unroll
  for (int off = 32; off > 0; off >>= 1) {
    s  += __shfl_xor(s, off, 64);
    sq += __shfl_xor(sq, off, 64);
  }
  const float mu   = s * (1.0f / C_DIM);
  const float var  = sq * (1.0f / C_DIM) - mu * mu;
  const float rstd = rsqrtf(var + 1e-5f);
  const f32x4* g4 = reinterpret_cast<const f32x4*>(g);
  const f32x4* b4 = reinterpret_cast<const f32x4*>(b);
  f16x4* h4 = reinterpret_cast<f16x4*>(h + (size_t)row * C_DIM);
#pragma unroll
  for (int i = 0; i < 4; ++i) {
    f32x4 gg = g4[i * 64 + lane];
    f32x4 bb = b4[i * 64 + lane];
    f16x4 o;
#pragma unroll
    for (int j = 0; j < 4; ++j)
      o[j] = (_Float16)((v[i][j] - mu) * rstd * gg[j] + bb[j]);
    h4[i * 64 + lane] = o;
  }
}

// ---------------- time-shift mix, 3 outputs ----------------
__global__ __launch_bounds__(256) void mix3_kernel(const _Float16* __restrict__ h,
    const float* __restrict__ mk, const float* __restrict__ mv, const float* __restrict__ mr,
    _Float16* __restrict__ xk, _Float16* __restrict__ xv, _Float16* __restrict__ xr) {
  const int i  = blockIdx.x * 256 + threadIdx.x;   // [0, M_ROWS*128)
  const int m  = i >> 7;
  const int c0 = (i & 127) << 3;
  const int p  = m >> 13;
  const int t  = m & (T_SEQ - 1);
  const f16x8* h8 = reinterpret_cast<const f16x8*>(h);
  f16x8 hc = h8[i];
  f16x8 hp;
#pragma unroll
  for (int j = 0; j < 8; ++j) hp[j] = (_Float16)0.f;
  if (t) hp = h8[i - 128];
  f16x8 ok, ov, orr;
#pragma unroll
  for (int j = 0; j < 8; ++j) {
    const float hcf = (float)hc[j], hpf = (float)hp[j];
    const float a = mk[p * C_DIM + c0 + j];
    const float c = mv[p * C_DIM + c0 + j];
    const float d = mr[p * C_DIM + c0 + j];
    ok[j]  = (_Float16)(hcf * a + hpf * (1.f - a));
    ov[j]  = (_Float16)(hcf * c + hpf * (1.f - c));
    orr[j] = (_Float16)(hcf * d + hpf * (1.f - d));
  }
  reinterpret_cast<f16x8*>(xk)[i] = ok;
  reinterpret_cast<f16x8*>(xv)[i] = ov;
  reinterpret_cast<f16x8*>(xr)[i] = orr;
}

// ---------------- time-shift mix, 2 outputs ----------------
__global__ __launch_bounds__(256) void mix2_kernel(const _Float16* __restrict__ h,
    const float* __restrict__ mk, const float* __restrict__ mr,
    _Float16* __restrict__ xk, _Float16* __restrict__ xr) {
  const int i  = blockIdx.x * 256 + threadIdx.x;
  const int m  = i >> 7;
  const int c0 = (i & 127) << 3;
  const int p  = m >> 13;
  const int t  = m & (T_SEQ - 1);
  const f16x8* h8 = reinterpret_cast<const f16x8*>(h);
  f16x8 hc = h8[i];
  f16x8 hp;
#pragma unroll
  for (int j = 0; j < 8; ++j) hp[j] = (_Float16)0.f;
  if (t) hp = h8[i - 128];
  f16x8 ok, orr;
#pragma unroll
  for (int j = 0; j < 8; ++j) {
    const float hcf = (float)hc[j], hpf = (float)hp[j];
    const float a = mk[p * C_DIM + c0 + j];
    const float d = mr[p * C_DIM + c0 + j];
    ok[j]  = (_Float16)(hcf * a + hpf * (1.f - a));
    orr[j] = (_Float16)(hcf * d + hpf * (1.f - d));
  }
  reinterpret_cast<f16x8*>(xk)[i] = ok;
  reinterpret_cast<f16x8*>(xr)[i] = orr;
}

// ---------------- WKV parallel chunked scan, fused with a = sigmoid(r)*y -------
__global__ __launch_bounds__(1024, 1) void wkv_kernel(const _Float16* __restrict__ k,
    const _Float16* __restrict__ v, const _Float16* __restrict__ r,
    const float* __restrict__ td, const float* __restrict__ tf,
    _Float16* __restrict__ a_out) {
  __shared__ float sA[CHUNKS][64];
  __shared__ float sB[CHUNKS][64];
  __shared__ float sP[CHUNKS][64];
  const int tid   = threadIdx.x;
  const int chunk = tid >> 6;
  const int ch    = tid & 63;
  const int n     = blockIdx.x >> 4;     // 16 sequences
  const int cg    = blockIdx.x & 15;     // 16 channel groups of 64
  const int c     = cg * 64 + ch;
  const float w = -__expf(td[c]);
  const float u = tf[c];
  const size_t cbase = (size_t)n * T_SEQ * C_DIM + (size_t)chunk * CLEN * C_DIM + c;

  // ---- phase 1: local chunk scan from empty state (state only) ----
  float aa = 0.f, bb = 0.f, pp = -1e38f;
  for (int s = 0; s < CLEN; ++s) {
    const size_t idx = cbase + (size_t)s * C_DIM;
    const float kk = (float)k[idx];
    const float vv = (float)v[idx];
    const float ww2 = w + pp;
    const float p2  = fmaxf(ww2, kk);
    const float e1b = __expf(ww2 - p2);
    const float e2b = __expf(kk - p2);
    aa = e1b * aa + e2b * vv;
    bb = e1b * bb + e2b;
    pp = p2;
  }
  sA[chunk][ch] = aa; sB[chunk][ch] = bb; sP[chunk][ch] = pp;
  __syncthreads();

  // ---- phase 2: exclusive prefix across chunks ----
  if (chunk == 0) {
    float pa = 0.f, pb = 0.f, ppr = -1e38f;
    const float wL = w * (float)CLEN;
    for (int j = 0; j < CHUNKS; ++j) {
      const float la = sA[j][ch], lb = sB[j][ch], lp = sP[j][ch];
      sA[j][ch] = pa; sB[j][ch] = pb; sP[j][ch] = ppr;
      const float dp = wL + ppr;
      const float np = fmaxf(dp, lp);
      const float e1 = __expf(dp - np);
      const float e2 = __expf(lp - np);
      pa  = e1 * pa + e2 * la;
      pb  = e1 * pb + e2 * lb;
      ppr = np;
    }
  }
  __syncthreads();

  // ---- phase 3: re-scan chunk from prefix state, emit sigmoid(r)*y ----
  aa = sA[chunk][ch]; bb = sB[chunk][ch]; pp = sP[chunk][ch];
  for (int s = 0; s < CLEN; ++s) {
    const size_t idx = cbase + (size_t)s * C_DIM;
    const float kk = (float)k[idx];
    const float vv = (float)v[idx];
    const float ww = u + kk;
    const float p  = fmaxf(pp, ww);
    const float e1 = __expf(pp - p);
    const float e2 = __expf(ww - p);
    const float yv = __fdividef(e1 * aa + e2 * vv, e1 * bb + e2);
    const float sr = sigmoidf_((float)r[idx]);
    a_out[idx] = (_Float16)(sr * yv);
    const float ww2 = w + pp;
    const float p2  = fmaxf(ww2, kk);
    const float e1b = __expf(ww2 - p2);
    const float e2b = __expf(kk - p2);
    aa = e1b * aa + e2b * vv;
    bb = e1b * bb + e2b;
    pp = p2;
  }
}

// ============ 256x256 GEMM, m201-style 4-phase-per-K-tile pipeline ============
// C[M,N] = A[M,K] * B[N,K]^T.  512 threads = 8 waves (2M x 4N), per-wave
// 128x64 output, BK=64, double-buffered LDS (128 KiB).
// Per K-tile t (buffer bi), 4 phases; each phase: {issue phase reads ||
// issue 1 half-tile stage (2 gload_lds) -> barrier -> lgkmcnt(0) ->
// setprio(1) -> 16 MFMA -> setprio(0) -> barrier}. Waves sit in ADJACENT
// phases, so one wave's ds_reads overlap another's MFMA (the m196/m201
// lever). Swap-phase P0 reads are POST-barrier (pre-barrier would race
// with other waves' unlanded stages — R4's bug). vmcnt ledger (uniform):
// stages of t+1 = 2 loads at each of P0..P3; at t's P0 after issuing 2,
// vmcnt(2) forces all 8 of tile t landed, keeps the 2 new in flight;
// last tile drains with vmcnt(0). Wave (wr,wcn) reads only A-half wr and
// B-half wcn>>1, both covered by the tile gate.
// T2 swizzle via pre-swizzled global SOURCE (linear LDS dest, rule 21) +
// same XOR on ds_read. A-fragments reuse one reg block (af dead after P1,
// re-read at P2) to bound VGPR.
// EPI 0: f16; 1: f16(relu^2); 2: f32 acc+X; 3: f32 X + sigmoid(acc)*KV
#define GBAR() do { __builtin_amdgcn_sched_barrier(0); \
                    __builtin_amdgcn_s_barrier(); \
                    __builtin_amdgcn_sched_barrier(0); } while (0)
#define WVN(n) do { asm volatile("s_waitcnt vmcnt(" #n ")" ::: "memory"); \
                    __builtin_amdgcn_sched_barrier(0); } while (0)
#define WLN(n) do { asm volatile("s_waitcnt lgkmcnt(" #n ")" ::: "memory"); \
                    __builtin_amdgcn_sched_barrier(0); } while (0)
#define STAGE(op, SRC, row0, k0, bb) do { \
    _Pragma("unroll") \
    for (int c_ = 0; c_ < 2; ++c_) { \
      gload_lds16((SRC) + (size_t)((row0) + c_ * 64) * K + (k0), \
                  &lds[bb][op][((size_t)((row0) + c_ * 64) << 6) + dbase]); \
    } } while (0)
#define RD_AH(dst, mh) do { \
    _Pragma("unroll") for (int i_ = 0; i_ < 4; ++i_) \
    _Pragma("unroll") for (int k_ = 0; k_ < 2; ++k_) \
      dst[i_][k_] = *reinterpret_cast<const f16x8*>( \
        &lds[bi][0][((wr * 128 + (mh) * 64 + i_ * 16 + frow) << 6) + \
                    (((k_ << 5) + fk) ^ fxorh)]); \
  } while (0)
#define RD_BH(dst, nh) do { \
    _Pragma("unroll") for (int j_ = 0; j_ < 2; ++j_) \
    _Pragma("unroll") for (int k_ = 0; k_ < 2; ++k_) \
      dst[j_][k_] = *reinterpret_cast<const f16x8*>( \
        &lds[bi][1][((wcn * 64 + (nh) * 32 + j_ * 16 + frow) << 6) + \
                    (((k_ << 5) + fk) ^ fxorh)]); \
  } while (0)
#define MM16(asrc, bsrc, mh, nh) do { \
    __builtin_amdgcn_s_setprio(1); \
    _Pragma("unroll") for (int k_ = 0; k_ < 2; ++k_) \
    _Pragma("unroll") for (int i_ = 0; i_ < 4; ++i_) \
    _Pragma("unroll") for (int j_ = 0; j_ < 2; ++j_) \
      acc[(mh) * 4 + i_][(nh) * 2 + j_] = __builtin_amdgcn_mfma_f32_16x16x32_f16( \
        asrc[i_][k_], bsrc[j_][k_], acc[(mh) * 4 + i_][(nh) * 2 + j_], 0, 0, 0); \
    __builtin_amdgcn_s_setprio(0); \
  } while (0)

template<int EPI>
__global__ __launch_bounds__(512, 2) void gemm_nt_256(
    const _Float16* __restrict__ A, const _Float16* __restrict__ B,
    void* __restrict__ Cv, const float* __restrict__ X,
    const _Float16* __restrict__ KV, int M, int N, int K) {
  __shared__ _Float16 lds[2][2][256 * 64];
  const int tid  = threadIdx.x;
  const int wave = tid >> 6;
  const int lane = tid & 63;
  const int wr   = wave >> 2;     // 0..1
  const int wcn  = wave & 3;      // 0..3

  // XCD-bijective swizzle: XCD owns contiguous M chunk, n-fastest within.
  const unsigned nwx  = gridDim.x;        // N/256
  const unsigned pery = gridDim.y >> 3;   // m-tiles per XCD
  const unsigned id   = blockIdx.y * nwx + blockIdx.x;
  const unsigned xcd  = id & 7;
  const unsigned loc  = id >> 3;
  const size_t m0 = (size_t)(xcd * pery + loc / nwx) * 256;
  const size_t n0 = (size_t)(loc % nwx) * 256;

  // staging geometry: half-tile = 128 rows x 64 halfs; wave w covers rows
  // {row0 + c*64 + w*8 .. +7}; LDS dest is wave-uniform base + lane*16B.
  const int srow  = tid >> 3;                       // 0..63
  const int scolh = ((tid & 7) ^ (srow & 7)) << 3;  // source-swizzled col (halfs)
  const size_t dbase = (size_t)(srow & ~7) << 6;    // wave-uniform
  const _Float16* sA = A + (m0 + srow) * (size_t)K + scolh;
  const _Float16* sB = B + (n0 + srow) * (size_t)K + scolh;

  // fragment geometry
  const int frow  = lane & 15;
  const int fk    = (lane >> 4) << 3;
  const int fxorh = (frow & 7) << 3;

  f32x4 acc[8][4];
#pragma unroll
  for (int i = 0; i < 8; ++i)
#pragma unroll
    for (int j = 0; j < 4; ++j) acc[i][j] = (f32x4){0.f, 0.f, 0.f, 0.f};

  // prologue: stage tile 0 -> buf 0 (8 loads/wave outstanding)
  STAGE(0, sA, 0, 0, 0); STAGE(0, sA, 128, 0, 0);
  STAGE(1, sB, 0, 0, 0); STAGE(1, sB, 128, 0, 0);

  const int NT = K >> 6;
  for (int t = 0; t < NT; ++t) {
    const int bi = t & 1;
    const int nb = bi ^ 1;
    const int k1 = (t + 1) << 6;
    const bool st = (t + 1) < NT;
    f16x8 af[4][2], b0f[2][2], b1f[2][2];
    // ---- P0 (swap phase): reads post-barrier ----
    if (st) { STAGE(0, sA, 0, k1, nb); WVN(2); }
    else    { WVN(0); }
    GBAR();
    RD_AH(af, 0); RD_BH(b0f, 0);
    WLN(0);
    MM16(af, b0f, 0, 0);
    GBAR();
    // ---- P1 ----
    RD_BH(b1f, 1);
    if (st) STAGE(1, sB, 0, k1, nb);
    GBAR();
    WLN(0);
    MM16(af, b1f, 0, 1);
    GBAR();
    // ---- P2 (af reused for A-half 1) ----
    RD_AH(af, 1);
    if (st) STAGE(1, sB, 128, k1, nb);
    GBAR();
    WLN(0);
    MM16(af, b0f, 1, 0);
    GBAR();
    // ---- P3 (pure MFMA) ----
    if (st) STAGE(0, sA, 128, k1, nb);
    GBAR();
    WLN(0);
    MM16(af, b1f, 1, 1);
    GBAR();
  }

  // epilogue: C/D layout (16x16): col = lane&15, row = (lane>>4)*4 + reg
  const int ecol  = lane & 15;
  const int erow4 = (lane >> 4) * 4;
#pragma unroll
  for (int mf = 0; mf < 8; ++mf)
#pragma unroll
    for (int nf = 0; nf < 4; ++nf) {
      const size_t rbase = m0 + (size_t)(wr * 128 + mf * 16 + erow4);
      const size_t cc    = n0 + (size_t)(wcn * 64 + nf * 16 + ecol);
#pragma unroll
      for (int r = 0; r < 4; ++r) {
        const float val = acc[mf][nf][r];
        const size_t off = (rbase + r) * (size_t)N + cc;
        if constexpr (EPI == 0) {
          ((_Float16*)Cv)[off] = (_Float16)val;
        } else if constexpr (EPI == 1) {
          const float tq = fmaxf(val, 0.f);
          ((_Float16*)Cv)[off] = (_Float16)(tq * tq);
        } else if constexpr (EPI == 2) {
          ((float*)Cv)[off] = val + X[off];
        } else {
          ((float*)Cv)[off] = X[off] + sigmoidf_(val) * (float)KV[off];
        }
      }
    }
}

extern "C" void kernel_launch(void* const* d_in, const int* in_sizes, int n_in,
                              void* d_out, int out_size, void* d_ws, size_t ws_size,
                              hipStream_t stream) {
  const float* x      = (const float*)d_in[0];
  const float* ln1_g  = (const float*)d_in[1];
  const float* ln1_b  = (const float*)d_in[2];
  const float* ln2_g  = (const float*)d_in[3];
  const float* ln2_b  = (const float*)d_in[4];
  const float* tdec   = (const float*)d_in[5];
  const float* tfirst = (const float*)d_in[6];
  const float* amk    = (const float*)d_in[7];
  const float* amv    = (const float*)d_in[8];
  const float* amr    = (const float*)d_in[9];
  const float* Wk     = (const float*)d_in[10];
  const float* Wv     = (const float*)d_in[11];
  const float* Wr     = (const float*)d_in[12];
  const float* Wo     = (const float*)d_in[13];
  const float* cmk    = (const float*)d_in[14];
  const float* cmr    = (const float*)d_in[15];
  const float* Wck    = (const float*)d_in[16];
  const float* Wcr    = (const float*)d_in[17];
  const float* Wcv    = (const float*)d_in[18];

  char* ws = (char*)d_ws;
  const size_t SZ = (size_t)M_ROWS * C_DIM * sizeof(_Float16);  // 32 MiB
  _Float16* B0 = (_Float16*)(ws + 0 * SZ);
  _Float16* B1 = (_Float16*)(ws + 1 * SZ);
  _Float16* B2 = (_Float16*)(ws + 2 * SZ);
  _Float16* B3 = (_Float16*)(ws + 3 * SZ);   // kk spans B3..B6 (128 MiB)
  _Float16* B4 = (_Float16*)(ws + 4 * SZ);
  _Float16* B5 = (_Float16*)(ws + 5 * SZ);
  _Float16* B6 = (_Float16*)(ws + 6 * SZ);
  _Float16* wWk  = (_Float16*)(ws + 7 * SZ);
  _Float16* wWv  = wWk  + (size_t)C_DIM * C_DIM;
  _Float16* wWr  = wWv  + (size_t)C_DIM * C_DIM;
  _Float16* wWo  = wWr  + (size_t)C_DIM * C_DIM;
  _Float16* wWcr = wWo  + (size_t)C_DIM * C_DIM;
  _Float16* wWck = wWcr + (size_t)C_DIM * C_DIM;
  _Float16* wWcv = wWck + (size_t)H_DIM * C_DIM;

  // fused weight cast: one launch for all 7 weights
  {
    CvtArgs a;
    const float* srcs[7] = {Wk, Wv, Wr, Wo, Wcr, Wck, Wcv};
    _Float16*    dsts[7] = {wWk, wWv, wWr, wWo, wWcr, wWck, wWcv};
    const size_t ns[7]   = {(size_t)C_DIM * C_DIM, (size_t)C_DIM * C_DIM,
                            (size_t)C_DIM * C_DIM, (size_t)C_DIM * C_DIM,
                            (size_t)C_DIM * C_DIM, (size_t)H_DIM * C_DIM,
                            (size_t)C_DIM * H_DIM};
    int st = 0;
    for (int j = 0; j < 7; ++j) {
      a.src[j] = srcs[j]; a.dst[j] = dsts[j];
      a.n4[j] = (int)(ns[j] / 4);
      a.start[j] = st;
      st += (a.n4[j] + 255) / 256;
    }
    a.start[7] = st;
    cvt_all_kernel<<<dim3(st), dim3(256), 0, stream>>>(a);
  }

  const dim3 blk(256);
  const dim3 gblk(512);
  const dim3 gN1(C_DIM / 256, M_ROWS / 256);   // (4, 64)
  const dim3 gN4(H_DIM / 256, M_ROWS / 256);   // (16, 64)

  // --- TimeMix ---
  ln_kernel<<<dim3(M_ROWS / 4), blk, 0, stream>>>(x, ln1_g, ln1_b, B0);
  mix3_kernel<<<dim3(M_ROWS * 128 / 256), blk, 0, stream>>>(B0, amk, amv, amr, B1, B2, B3);
  gemm_nt_256<0><<<gN1, gblk, 0, stream>>>(B1, wWk, B4, nullptr, nullptr, M_ROWS, C_DIM, C_DIM);
  gemm_nt_256<0><<<gN1, gblk, 0, stream>>>(B2, wWv, B5, nullptr, nullptr, M_ROWS, C_DIM, C_DIM);
  gemm_nt_256<0><<<gN1, gblk, 0, stream>>>(B3, wWr, B6, nullptr, nullptr, M_ROWS, C_DIM, C_DIM);
  wkv_kernel<<<dim3(256), dim3(1024), 0, stream>>>(B4, B5, B6, tdec, tfirst, B1);
  gemm_nt_256<2><<<gN1, gblk, 0, stream>>>(B1, wWo, d_out, x, nullptr, M_ROWS, C_DIM, C_DIM);

  // --- ChannelMix ---
  ln_kernel<<<dim3(M_ROWS / 4), blk, 0, stream>>>((const float*)d_out, ln2_g, ln2_b, B0);
  mix2_kernel<<<dim3(M_ROWS * 128 / 256), blk, 0, stream>>>(B0, cmk, cmr, B1, B2);
  gemm_nt_256<1><<<gN4, gblk, 0, stream>>>(B1, wWck, B3, nullptr, nullptr, M_ROWS, H_DIM, C_DIM);
  gemm_nt_256<0><<<gN1, gblk, 0, stream>>>(B3, wWcv, B1, nullptr, nullptr, M_ROWS, C_DIM, H_DIM);
  gemm_nt_256<3><<<gN1, gblk, 0, stream>>>(B2, wWcr, d_out, (const float*)d_out, B1,
                                           M_ROWS, C_DIM, C_DIM);
}